// Round 9
// baseline (20451.067 us; speedup 1.0000x reference)
//
#include <hip/hip_runtime.h>

#define B_ 32
#define S_ 64
#define V_ 96
#define E_ 256
#define H_ 512
#define L_ 3
#define DIN_ 1024
#define G4_ 2048
#define BH_ (B_*H_)
#define BDIN_ (B_*DIN_)
#define FSTRIDE 16   // flags spaced 64B apart

typedef unsigned short u16;

__device__ __forceinline__ float bfu(u16 u){ return __uint_as_float(((unsigned)u) << 16); }
__device__ __forceinline__ u16 f2b(float f){           // RNE float->bf16
  unsigned x = __float_as_uint(f);
  unsigned r = (x + 0x7FFFu + ((x >> 16) & 1u)) >> 16;
  return (u16)r;
}
__device__ __forceinline__ float sigm(float x){ return 1.f/(1.f+__expf(-x)); }
__device__ __forceinline__ float bsum(float a){
  #pragma unroll
  for(int off=1; off<64; off<<=1) a += __shfl_xor(a, off);
  return a;
}
// Coherent (LLC-point) access: relaxed agent-scope atomics emit sc0/sc1
// load/store -- per-access coherence, NO cache wb/inv instructions.
__device__ __forceinline__ void stc(float* p, float v){
  __hip_atomic_store(p, v, __ATOMIC_RELAXED, __HIP_MEMORY_SCOPE_AGENT);
}
__device__ __forceinline__ float ldc(const float* p){
  return __hip_atomic_load((float*)p, __ATOMIC_RELAXED, __HIP_MEMORY_SCOPE_AGENT);
}
__device__ __forceinline__ void stci(int* p, int v){
  __hip_atomic_store(p, v, __ATOMIC_RELAXED, __HIP_MEMORY_SCOPE_AGENT);
}
__device__ __forceinline__ int ldci(const int* p){
  return __hip_atomic_load((int*)p, __ATOMIC_RELAXED, __HIP_MEMORY_SCOPE_AGENT);
}
// Dual-dtype INPUT loads. BF=1: buffer is bf16 (u16); BF=0: buffer is fp32.
template<int BF> __device__ __forceinline__ float LD(const void* p, size_t i){
  if constexpr(BF) return bfu(((const u16*)p)[i]);
  else             return ((const float*)p)[i];
}
template<int BF> __device__ __forceinline__ float4 LD4(const void* p, size_t i){
  if constexpr(BF){
    const u16* q = (const u16*)p + i;
    ushort4 w = *(const ushort4*)q;
    return make_float4(bfu(w.x), bfu(w.y), bfu(w.z), bfu(w.w));
  } else {
    return *(const float4*)((const float*)p + i);
  }
}

// ---------------------------------------------------------------------------
// Distributed contention-free grid barrier (round-4 proven).
__device__ __forceinline__ void gbar(int* flags, int g){
  __syncthreads();
  if(threadIdx.x < 64){
    if(threadIdx.x == 0) stci(&flags[blockIdx.x*FSTRIDE], g);
    const int i0 = threadIdx.x*4;
    for(;;){
      int f0 = ldci(&flags[(i0+0)*FSTRIDE]);
      int f1 = ldci(&flags[(i0+1)*FSTRIDE]);
      int f2 = ldci(&flags[(i0+2)*FSTRIDE]);
      int f3 = ldci(&flags[(i0+3)*FSTRIDE]);
      bool ok = (f0>=g) && (f1>=g) && (f2>=g) && (f3>=g);
      if(__all(ok)) break;
      __builtin_amdgcn_s_sleep(1);
    }
  }
  __syncthreads();
}

// ---------------------------------------------------------------------------
__global__ void k_detect(const void* av, int* flag, int* flags){
  __shared__ int cnt;
  if(threadIdx.x == 0) cnt = 0;
  __syncthreads();
  u16 w = ((const u16*)av)[2*threadIdx.x];
  if(w & 0x8000) atomicAdd(&cnt, 1);
  __syncthreads();
  for(int i=threadIdx.x; i<256*FSTRIDE+16; i+=256) flags[i] = 0;
  if(threadIdx.x == 0) *flag = (cnt <= 8) ? 1 : 0;   // 1 = bf16 inputs
}

// ---------------------------------------------------------------------------
template<int BF> __device__ void embed_body(const int* __restrict__ src,
                                            const void* __restrict__ emb,
                                            float* __restrict__ X0){
  int idx = blockIdx.x*256 + threadIdx.x;   // exactly S*B*DIN threads
  int d  = idx & (DIN_-1);
  int sb = idx >> 10;
  int b  = sb & (B_-1);
  int s  = sb >> 5;
  float v = 0.f;
  if(d < E_){
    int tok = src[b*S_ + s];
    v = LD<BF>(emb, (size_t)tok*E_ + d);
  }
  X0[idx] = v;
}
__global__ void k_embed(const int* src, const void* emb, float* X0, const int* fl){
  if(*fl) embed_body<1>(src, emb, X0); else embed_body<0>(src, emb, X0);
}

// ---------------------------------------------------------------------------
// Tiled GEMM: C[m,n] = sum_k A[m*lda+k] * W[woff + n*ldw + k] + b1[n] + b2[n]
template<int BF> __device__ void gemm_body(
  const float* __restrict__ A, int lda,
  const void* __restrict__ W, int ldw, size_t woff,
  const void* __restrict__ b1, size_t o1,
  const void* __restrict__ b2, size_t o2,
  float* __restrict__ C, int ldc, int K)
{
  __shared__ float As[16][128];
  __shared__ float Bs[16][64];
  const int tid = threadIdx.x;
  const int m0 = blockIdx.y * 128;
  const int n0 = blockIdx.x * 64;
  const int tx = tid & 15, ty = tid >> 4;
  const int amm = tid & 127, akk = (tid >> 7) * 8;
  const int bnn = tid >> 2,  bkk = (tid & 3) * 4;
  float acc[8][4] = {{0.f}};
  for(int k0 = 0; k0 < K; k0 += 16){
    const float4* ap = (const float4*)(A + (size_t)(m0+amm)*lda + (k0 + akk));
    float4 a0 = ap[0];
    float4 a1 = ap[1];
    float4 wv = LD4<BF>(W, woff + (size_t)(n0+bnn)*ldw + (k0 + bkk));
    As[akk+0][amm]=a0.x; As[akk+1][amm]=a0.y; As[akk+2][amm]=a0.z; As[akk+3][amm]=a0.w;
    As[akk+4][amm]=a1.x; As[akk+5][amm]=a1.y; As[akk+6][amm]=a1.z; As[akk+7][amm]=a1.w;
    Bs[bkk+0][bnn]=wv.x; Bs[bkk+1][bnn]=wv.y;
    Bs[bkk+2][bnn]=wv.z; Bs[bkk+3][bnn]=wv.w;
    __syncthreads();
    #pragma unroll
    for(int kk=0;kk<16;kk++){
      const float4 av0 = *(const float4*)&As[kk][ty*8];
      const float4 av1 = *(const float4*)&As[kk][ty*8+4];
      const float4 bv  = *(const float4*)&Bs[kk][tx*4];
      float am[8] = {av0.x,av0.y,av0.z,av0.w,av1.x,av1.y,av1.z,av1.w};
      float bn[4] = {bv.x,bv.y,bv.z,bv.w};
      #pragma unroll
      for(int i=0;i<8;i++){
        #pragma unroll
        for(int j=0;j<4;j++) acc[i][j] = fmaf(am[i], bn[j], acc[i][j]);
      }
    }
    __syncthreads();
  }
  float bias[4];
  #pragma unroll
  for(int j=0;j<4;j++){
    float bb = 0.f;
    if(b1) bb += LD<BF>(b1, o1 + n0 + tx*4 + j);
    if(b2) bb += LD<BF>(b2, o2 + n0 + tx*4 + j);
    bias[j] = bb;
  }
  #pragma unroll
  for(int i=0;i<8;i++){
    float* cp = C + (size_t)(m0 + ty*8 + i)*ldc + (n0 + tx*4);
    #pragma unroll
    for(int j=0;j<4;j++) cp[j] = acc[i][j] + bias[j];
  }
}
__global__ __launch_bounds__(256) void k_gemm(
  const float* A, int lda, const void* W, int ldw, size_t woff,
  const void* b1, size_t o1, const void* b2, size_t o2,
  float* C, int ldc, int K, const int* fl)
{
  if(*fl) gemm_body<1>(A,lda,W,ldw,woff,b1,o1,b2,o2,C,ldc,K);
  else    gemm_body<0>(A,lda,W,ldw,woff,b1,o1,b2,o2,C,ldc,K);
}

// ---------------------------------------------------------------------------
__global__ void k_outzero(void* __restrict__ out, const int* fl){
  int i = blockIdx.x*256 + threadIdx.x;
  if(i < B_*V_){
    int b = i / V_, v = i % V_;
    size_t idx = (size_t)b*(S_*V_) + v;
    if(*fl) ((u16*)out)[idx] = 0;
    else    ((float*)out)[idx] = 0.f;
  }
}

// ===========================================================================
// ENCODER (round-8 proven, unchanged): 512-thread wave-pair persistent kernel.
// ===========================================================================
struct EncArgs2 {
  const float* G;
  const void* Whh; size_t oWh;
  float* henc;   // [64 gen-slots][2 dir][BH] fp32  (slot = gen & 63)
  float* cT;     // [2 dir][j*32+b] coherent
  float* Xout;   // [(t*B+b)][DIN]
  float* dh0;    // decoder h init [3][BH]
  float* dcT;    // decoder c init [3][j*32+b]
  int l;
  const int* fl;
  int* flags; int gbase;
};

template<int BF>
__device__ void enc2_body(const EncArgs2& a){
  __shared__ float SM[16384];
  const int tid  = threadIdx.x;
  const int lane = tid & 63;
  const int wid  = tid >> 6;                 // 0..7
  const int w4   = (blockIdx.x<<2) + (wid & 3);
  const int j    = w4 & 511;
  const int d    = w4 >> 9;
  const int half = wid >> 2;                 // wave-pair half
  int g = a.gbase;

  float wh[4][8];
  #pragma unroll
  for(int gg=0; gg<4; gg++){
    size_t rowh = a.oWh + ((size_t)d*G4_ + (size_t)gg*H_ + j)*H_;
    #pragma unroll
    for(int p=0;p<2;p++){
      float4 v = LD4<BF>(a.Whh, rowh + (lane<<2) + p*256);
      wh[gg][p*4+0]=v.x; wh[gg][p*4+1]=v.y; wh[gg][p*4+2]=v.z; wh[gg][p*4+3]=v.w;
    }
  }
  const bool own = (lane < 32) && ((lane>>4) == half);   // this wave's batches
  const size_t ci = ((size_t)d*H_ + j)*32 + (lane & 31);
  float cv = 0.f;

  for(int p=0;p<64;p++){
    const int t = d ? (63-p) : p;
    if(p == 0){
      for(int i=tid<<2; i<BH_; i+=2048) *(float4*)&SM[i] = make_float4(0.f,0.f,0.f,0.f);
    } else {
      const float* hsrc = a.henc + (size_t)((p&63)*2 + d)*BH_;  // slot p, fresh
      for(int i=tid<<2; i<BH_; i+=2048) *(float4*)&SM[i] = *(const float4*)&hsrc[i];
    }
    __syncthreads();

    const int bE = lane & 31;
    const float* Gp = a.G + (size_t)(t*B_+bE)*4096 + (size_t)d*G4_ + j;
    float pg0=Gp[0], pg1=Gp[512], pg2=Gp[1024], pg3=Gp[1536];

    float gv0=0.f, gv1=0.f, gv2=0.f, gv3=0.f;
    for(int b=half*16; b<half*16+16; b++){
      float gs[4] = {0.f,0.f,0.f,0.f};
      const float* hp = &SM[(b<<9) + (lane<<2)];
      #pragma unroll
      for(int pp=0;pp<2;pp++){
        float4 hv = *(const float4*)(hp + pp*256);
        float ha[4] = {hv.x,hv.y,hv.z,hv.w};
        #pragma unroll
        for(int gg=0;gg<4;gg++){
          #pragma unroll
          for(int i=0;i<4;i++) gs[gg] = fmaf(ha[i], wh[gg][pp*4+i], gs[gg]);
        }
      }
      #pragma unroll
      for(int gg=0;gg<4;gg++) gs[gg] = bsum(gs[gg]);
      if(lane == b){ gv0=gs[0]; gv1=gs[1]; gv2=gs[2]; gv3=gs[3]; }
    }
    if(own){
      float gi = gv0+pg0, gf = gv1+pg1, gG = gv2+pg2, go = gv3+pg3;
      float c2 = sigm(gf)*cv + sigm(gi)*tanhf(gG);
      float h2 = sigm(go)*tanhf(c2);
      cv = c2;
      stc(&a.henc[(size_t)(((p+1)&63)*2 + d)*BH_ + (size_t)lane*H_ + j], h2);
      a.Xout[(size_t)(t*B_+lane)*DIN_ + (d<<9) + j] = h2;
    }
    gbar(a.flags, ++g);
  }
  if(own) stc(&a.cT[ci], cv);
  gbar(a.flags, ++g);
  for(int i = blockIdx.x*512 + tid; i < BH_; i += 131072){
    float hf2 = a.henc[(size_t)(0*2+0)*BH_ + i];
    float hb2 = a.henc[(size_t)(0*2+1)*BH_ + i];
    a.dh0[(size_t)a.l*BH_ + i] = hf2 + hb2;
    a.dcT[(size_t)a.l*BH_ + i] = ldc(&a.cT[i]) + ldc(&a.cT[BH_ + i]);
  }
}
__global__ __launch_bounds__(512,1) void k_enc2(EncArgs2 a){
  if(*a.fl) enc2_body<1>(a); else enc2_body<0>(a);
}

// ===========================================================================
// DECODER (plan A5): 4 phases/step.
//  Phase1 (32 att blocks, batch b each): fc(t-1) + z + scores + softmax + ctx
//    + proj -> xpb[t] (all block-local in LDS; zb/ctxb eliminated).
//  cells 0..2: 256 blocks, 2048 waves = 512 jp x 4 batch-quarters (8 batches
//    per block, 8 DISTINCT jp per block -- no duplicate weight loads).
//  Cell weights are preloaded into registers BEFORE the preceding gbar, so
//  their fetch latency hides under the barrier wait.
// ===========================================================================
struct DecArgs2 {
  const int* trg;
  const void* emb; const void* aW; const void* av; const void* pW; const void* pb;
  const void* dWih; const void* dWhh; const void* dbih; const void* dbhh;
  const void* fW; const void* fb;
  const float* Epre; const float* X3;
  const float* dh0;   // [3][BH] initial h (from encoder)
  float* dhb;   // [64 t-slots][3][BH] fp32 (slot t = state entering step t)
  float* xpb;   // [63][B][DIN] fp32
  const float* dcT;  // [3][j*32+b]
  void* out;
  const int* fl;
  int* flags; int gbase;
};

template<int BF, int CP>
__device__ __forceinline__ void dec_loadW(const DecArgs2& a, const int l,
    const int jp, const int lane, float wx[4][16], float wh[4][8], float pg[4]){
  #pragma unroll
  for(int gg=0; gg<4; gg++){
    size_t rowx = ((size_t)l*G4_ + (size_t)gg*H_ + jp)*DIN_;
    #pragma unroll
    for(int p=0;p<CP;p++){
      float4 v = LD4<BF>(a.dWih, rowx + (lane<<2) + p*256);
      wx[gg][p*4+0]=v.x; wx[gg][p*4+1]=v.y; wx[gg][p*4+2]=v.z; wx[gg][p*4+3]=v.w;
    }
    size_t rowh = ((size_t)l*G4_ + (size_t)gg*H_ + jp)*H_;
    #pragma unroll
    for(int p=0;p<2;p++){
      float4 v = LD4<BF>(a.dWhh, rowh + (lane<<2) + p*256);
      wh[gg][p*4+0]=v.x; wh[gg][p*4+1]=v.y; wh[gg][p*4+2]=v.z; wh[gg][p*4+3]=v.w;
    }
  }
  size_t bb = (size_t)l*G4_ + jp;
  #pragma unroll
  for(int gg=0;gg<4;gg++)
    pg[gg] = LD<BF>(a.dbih, bb + (size_t)gg*H_) + LD<BF>(a.dbhh, bb + (size_t)gg*H_);
}

template<int BF, int CP>   // Kx = CP*256
__device__ __forceinline__ void dec_cellc(const DecArgs2& a, float* SM,
    const int t, const int l, const int jp, const int bq,
    const int lane, const int tid,
    float wx[4][16], float wh[4][8], float pg[4], float& cv){
  constexpr int Kx = CP*256;
  const float* xsrc = (l==0) ? (a.xpb + (size_t)t*BDIN_ + (size_t)bq*8*DIN_)
                             : (a.dhb + (size_t)((t+1)*3 + (l-1))*BH_ + (size_t)bq*8*H_);
  const float* hsrc = (t==0) ? (a.dh0 + (size_t)l*BH_ + (size_t)bq*8*H_)
                             : (a.dhb + (size_t)(t*3 + l)*BH_ + (size_t)bq*8*H_);
  for(int i=tid<<2; i<8*Kx; i+=2048) *(float4*)&SM[i] = *(const float4*)&xsrc[i];
  for(int i=tid<<2; i<8*H_; i+=2048) *(float4*)&SM[8*Kx + i] = *(const float4*)&hsrc[i];
  __syncthreads();
  float gv0=0.f,gv1=0.f,gv2=0.f,gv3=0.f;
  for(int ib=0; ib<8; ib++){
    float gs[4] = {0.f,0.f,0.f,0.f};
    const float* xr = &SM[ib*Kx + (lane<<2)];
    #pragma unroll
    for(int p=0;p<CP;p++){
      float4 xv = *(const float4*)(xr + p*256);
      float xa[4] = {xv.x,xv.y,xv.z,xv.w};
      #pragma unroll
      for(int gg=0;gg<4;gg++){
        #pragma unroll
        for(int i=0;i<4;i++) gs[gg] = fmaf(xa[i], wx[gg][p*4+i], gs[gg]);
      }
    }
    const float* hr = &SM[8*Kx + ib*H_ + (lane<<2)];
    #pragma unroll
    for(int p=0;p<2;p++){
      float4 hv = *(const float4*)(hr + p*256);
      float ha[4] = {hv.x,hv.y,hv.z,hv.w};
      #pragma unroll
      for(int gg=0;gg<4;gg++){
        #pragma unroll
        for(int i=0;i<4;i++) gs[gg] = fmaf(ha[i], wh[gg][p*4+i], gs[gg]);
      }
    }
    #pragma unroll
    for(int gg=0;gg<4;gg++) gs[gg] = bsum(gs[gg]);
    if(lane == ib){ gv0=gs[0]; gv1=gs[1]; gv2=gs[2]; gv3=gs[3]; }
  }
  if(lane < 8){
    const int b = bq*8 + lane;
    float gi = gv0+pg[0], gf = gv1+pg[1], gG = gv2+pg[2], go = gv3+pg[3];
    float c2 = sigm(gf)*cv + sigm(gi)*tanhf(gG);
    float h2 = sigm(go)*tanhf(c2);
    cv = c2;
    stc(&a.dhb[(size_t)((t+1)*3 + l)*BH_ + (size_t)b*H_ + jp], h2);
  }
}

template<int BF>
__device__ void dec2_body(const DecArgs2& a){
  __shared__ float SM[12288];     // 48 KB: cell0 needs 8*1024 + 8*512 floats
  const int tid  = threadIdx.x;
  const int lane = tid & 63;
  const int wid  = tid >> 6;                 // 0..7
  const int w8   = (blockIdx.x<<3) + wid;    // 0..2047
  const int jp   = w8 & 511;
  const int bq   = w8 >> 9;                  // 0..3 (uniform per block)
  int g = a.gbase;

  float cvs[3];
  #pragma unroll
  for(int l=0;l<3;l++)
    cvs[l] = a.dcT[((size_t)l*H_ + jp)*32 + (size_t)bq*8 + (lane&7)];

  float wx[4][16], wh[4][8], pg[4];

  for(int t=0; t<64; ++t){
    // ---- Phase1: att blocks do fc(t-1) + z + att + ctx + proj(t) ----
    if(blockIdx.x < 32){
      const int b = blockIdx.x;
      float* Ht = SM;          // 512
      float* Zs = SM + 512;    // 512
      float* Cx = SM + 1024;   // 1024
      float* Ss = SM + 2048;   // 64 (+pad)
      float* Em = SM + 2176;   // 256
      const float* hs = (t==0) ? (a.dh0 + (size_t)2*BH_ + (size_t)b*H_)
                               : (a.dhb + (size_t)(t*3 + 2)*BH_ + (size_t)b*H_);
      Ht[tid] = hs[tid];
      __syncthreads();
      if(t > 0 && tid < 96){
        float acc = 0.f;
        size_t rf = (size_t)tid*H_;
        #pragma unroll 4
        for(int k=0;k<H_;k+=4){
          float4 wv = LD4<BF>(a.fW, rf + k);
          acc = fmaf(Ht[k],wv.x,acc); acc = fmaf(Ht[k+1],wv.y,acc);
          acc = fmaf(Ht[k+2],wv.z,acc); acc = fmaf(Ht[k+3],wv.w,acc);
        }
        float rr = acc + LD<BF>(a.fb, tid);
        size_t oi = (size_t)b*(S_*V_) + (size_t)t*V_ + tid;
        if constexpr(BF) ((u16*)a.out)[oi] = f2b(rr);
        else             ((float*)a.out)[oi] = rr;
      }
      if(t < 63){
        {   // z[tid] = dot(htop, aW[tid, 0:512])
          float acc = 0.f;
          size_t rz = (size_t)tid*1536;
          #pragma unroll 4
          for(int k=0;k<512;k+=4){
            float4 wv = LD4<BF>(a.aW, rz + k);
            acc = fmaf(Ht[k],wv.x,acc); acc = fmaf(Ht[k+1],wv.y,acc);
            acc = fmaf(Ht[k+2],wv.z,acc); acc = fmaf(Ht[k+3],wv.w,acc);
          }
          Zs[tid] = acc;
        }
        __syncthreads();
        {   // scores: wave wid handles s in [wid*8, wid*8+8)
          float wa[8];
          #pragma unroll
          for(int p=0;p<2;p++){
            float4 v = LD4<BF>(a.av, (lane<<2) + p*256);
            wa[p*4+0]=v.x; wa[p*4+1]=v.y; wa[p*4+2]=v.z; wa[p*4+3]=v.w;
          }
          for(int s=wid*8; s<wid*8+8; s++){
            const float* ep = a.Epre + ((size_t)(s*B_ + b))*H_;
            float acc = 0.f;
            #pragma unroll
            for(int p=0;p<2;p++){
              const float4 e4 = *(const float4*)(ep + (lane<<2) + p*256);
              const float4 z4 = *(const float4*)(Zs + (lane<<2) + p*256);
              acc = fmaf(wa[p*4+0], tanhf(e4.x+z4.x), acc);
              acc = fmaf(wa[p*4+1], tanhf(e4.y+z4.y), acc);
              acc = fmaf(wa[p*4+2], tanhf(e4.z+z4.z), acc);
              acc = fmaf(wa[p*4+3], tanhf(e4.w+z4.w), acc);
            }
            acc = bsum(acc);
            if(lane==0) Ss[s] = acc;
          }
        }
        __syncthreads();
        if(tid < 64){
          float vv = Ss[tid];
          float m = vv;
          #pragma unroll
          for(int off=1; off<64; off<<=1) m = fmaxf(m, __shfl_xor(m, off));
          float e = __expf(vv - m);
          float su = e;
          #pragma unroll
          for(int off=1; off<64; off<<=1) su += __shfl_xor(su, off);
          Ss[tid] = e / su;
        }
        __syncthreads();
        if(tid < 256){   // ctx
          int d4 = tid<<2;
          float a0=0.f,a1=0.f,a2=0.f,a3=0.f;
          const float* xb = a.X3 + (size_t)b*DIN_ + d4;
          #pragma unroll 4
          for(int s=0;s<64;s++){
            const float pp = Ss[s];
            const float4 xv = *(const float4*)(xb + (size_t)s*BDIN_);
            a0 = fmaf(pp, xv.x, a0); a1 = fmaf(pp, xv.y, a1);
            a2 = fmaf(pp, xv.z, a2); a3 = fmaf(pp, xv.w, a3);
          }
          *(float4*)&Cx[d4] = make_float4(a0,a1,a2,a3);
        }
        if(tid < 64){    // embedding row
          int tok = a.trg[b*S_ + t];
          float4 ev = LD4<BF>(a.emb, (size_t)tok*E_ + (tid<<2));
          *(float4*)&Em[tid<<2] = ev;
        }
        __syncthreads();
        {   // proj: thread -> outputs tid and tid+512
          #pragma unroll
          for(int jj=0;jj<2;jj++){
            const int j = tid + (jj<<9);
            size_t row = (size_t)j*1280;
            float acc = 0.f;
            #pragma unroll 4
            for(int k=0;k<256;k+=4){
              float4 wv = LD4<BF>(a.pW, row + k);
              acc = fmaf(Em[k],wv.x,acc); acc = fmaf(Em[k+1],wv.y,acc);
              acc = fmaf(Em[k+2],wv.z,acc); acc = fmaf(Em[k+3],wv.w,acc);
            }
            #pragma unroll 4
            for(int k=0;k<1024;k+=4){
              float4 wv = LD4<BF>(a.pW, row + 256 + k);
              acc = fmaf(Cx[k],wv.x,acc); acc = fmaf(Cx[k+1],wv.y,acc);
              acc = fmaf(Cx[k+2],wv.z,acc); acc = fmaf(Cx[k+3],wv.w,acc);
            }
            stc(&a.xpb[(size_t)t*BDIN_ + (size_t)b*DIN_ + j], acc + LD<BF>(a.pb, j));
          }
        }
      }
    }
    if(t == 63) break;

    // ---- cells (weights preloaded BEFORE each barrier) ----
    dec_loadW<BF,4>(a, 0, jp, lane, wx, wh, pg);
    gbar(a.flags, ++g);
    dec_cellc<BF,4>(a, SM, t, 0, jp, bq, lane, tid, wx, wh, pg, cvs[0]);
    dec_loadW<BF,2>(a, 1, jp, lane, wx, wh, pg);
    gbar(a.flags, ++g);
    dec_cellc<BF,2>(a, SM, t, 1, jp, bq, lane, tid, wx, wh, pg, cvs[1]);
    dec_loadW<BF,2>(a, 2, jp, lane, wx, wh, pg);
    gbar(a.flags, ++g);
    dec_cellc<BF,2>(a, SM, t, 2, jp, bq, lane, tid, wx, wh, pg, cvs[2]);
    gbar(a.flags, ++g);
  }
}
__global__ __launch_bounds__(512,1) void k_dec2(DecArgs2 a){
  if(*a.fl) dec2_body<1>(a); else dec2_body<0>(a);
}

// ===========================================================================
// PLAN B fallback (small workspace): round-4 proven kernels, verbatim.
// ===========================================================================
struct EncArgsO {
  const float* G;
  const float* Xin;
  const void* Wih; size_t oWi;
  const void* Whh; size_t oWh;
  const void* bih; size_t obi;
  const void* bhh; size_t obh;
  float* hst; float* cT; float* Xout; float* dh; float* dcT;
  int l; const int* fl; int* flags; int gbase;
};

template<int BF, int CP>
__device__ void encO_body(const EncArgsO& a){
  __shared__ float SM[16384];
  const int tid  = threadIdx.x;
  const int w    = (blockIdx.x<<2) + (tid>>6);
  const int lane = tid & 63;
  const int d    = w >> 9;
  const int j    = w & 511;
  int g = a.gbase;

  float wh[4][8];
  #pragma unroll
  for(int gg=0; gg<4; gg++){
    size_t rowh = a.oWh + ((size_t)d*G4_ + (size_t)gg*H_ + j)*H_;
    #pragma unroll
    for(int p=0;p<2;p++){
      float4 v = LD4<BF>(a.Whh, rowh + (lane<<2) + p*256);
      wh[gg][p*4+0]=v.x; wh[gg][p*4+1]=v.y; wh[gg][p*4+2]=v.z; wh[gg][p*4+3]=v.w;
    }
  }
  float wxf[4][CP?CP*4:1];
  float pbias[4];
  if constexpr(CP>0){
    #pragma unroll
    for(int gg=0; gg<4; gg++){
      size_t rowx = a.oWi + ((size_t)d*G4_ + (size_t)gg*H_ + j)*DIN_;
      #pragma unroll
      for(int p=0;p<CP;p++){
        float4 v = LD4<BF>(a.Wih, rowx + (lane<<2) + p*256);
        wxf[gg][p*4+0]=v.x; wxf[gg][p*4+1]=v.y; wxf[gg][p*4+2]=v.z; wxf[gg][p*4+3]=v.w;
      }
    }
    size_t bb = (size_t)d*G4_ + j;
    #pragma unroll
    for(int gg=0;gg<4;gg++)
      pbias[gg] = LD<BF>(a.bih, a.obi + bb + (size_t)gg*H_)
                + LD<BF>(a.bhh, a.obh + bb + (size_t)gg*H_);
  }
  const int bE = lane & 31;
  const size_t ci = ((size_t)d*H_ + j)*32 + bE;
  float cv = 0.f;
  int cur = 0;
  for(int p=0;p<64;p++){
    const int t = d ? (63-p) : p;
    if(p == 0){
      for(int i=tid<<2; i<BH_; i+=1024) *(float4*)&SM[i] = make_float4(0.f,0.f,0.f,0.f);
    } else {
      const float* hsrc = a.hst + (size_t)((cur<<1)+d)*BH_;
      #pragma unroll 4
      for(int i=tid; i<BH_; i+=256) SM[i] = ldc(hsrc + i);
    }
    __syncthreads();
    float pg[4];
    if constexpr(CP==0){
      const float* Gp = a.G + (size_t)(t*B_+bE)*4096 + (size_t)d*G4_ + j;
      pg[0]=Gp[0]; pg[1]=Gp[512]; pg[2]=Gp[1024]; pg[3]=Gp[1536];
    } else {
      pg[0]=pbias[0]; pg[1]=pbias[1]; pg[2]=pbias[2]; pg[3]=pbias[3];
    }
    const float* xrow = nullptr;
    if constexpr(CP>0) xrow = a.Xin + (size_t)t*B_*DIN_;
    float gv0=0.f, gv1=0.f, gv2=0.f, gv3=0.f;
    for(int b=0;b<32;b++){
      float gs[4] = {0.f,0.f,0.f,0.f};
      const float* hp = &SM[(b<<9) + (lane<<2)];
      #pragma unroll
      for(int pp=0;pp<2;pp++){
        float4 hv = *(const float4*)(hp + pp*256);
        float ha[4] = {hv.x,hv.y,hv.z,hv.w};
        #pragma unroll
        for(int gg=0;gg<4;gg++){
          #pragma unroll
          for(int i=0;i<4;i++) gs[gg] = fmaf(ha[i], wh[gg][pp*4+i], gs[gg]);
        }
      }
      if constexpr(CP>0){
        const float* xr = xrow + (size_t)b*DIN_ + (lane<<2);
        #pragma unroll
        for(int pp=0;pp<CP;pp++){
          float4 xv = *(const float4*)(xr + pp*256);
          float xa[4] = {xv.x,xv.y,xv.z,xv.w};
          #pragma unroll
          for(int gg=0;gg<4;gg++){
            #pragma unroll
            for(int i=0;i<4;i++) gs[gg] = fmaf(xa[i], wxf[gg][pp*4+i], gs[gg]);
          }
        }
      }
      #pragma unroll
      for(int gg=0;gg<4;gg++) gs[gg] = bsum(gs[gg]);
      if(lane == b){ gv0=gs[0]; gv1=gs[1]; gv2=gs[2]; gv3=gs[3]; }
    }
    if(lane < 32){
      float gi = gv0+pg[0], gf = gv1+pg[1], gG = gv2+pg[2], go = gv3+pg[3];
      float c2 = sigm(gf)*cv + sigm(gi)*tanhf(gG);
      float h2 = sigm(go)*tanhf(c2);
      cv = c2;
      stc(&a.hst[(size_t)(((cur^1)<<1)+d)*BH_ + (size_t)bE*H_ + j], h2);
      a.Xout[(size_t)(t*B_+bE)*DIN_ + (d<<9) + j] = h2;
    }
    gbar(a.flags, ++g);
    cur ^= 1;
  }
  if(lane < 32) stc(&a.cT[ci], cv);
  gbar(a.flags, ++g);
  for(int i = blockIdx.x*256 + tid; i < BH_; i += 65536){
    a.dh[(size_t)a.l*BH_ + i]  = ldc(&a.hst[(size_t)(cur<<1)*BH_ + i])
                               + ldc(&a.hst[(size_t)((cur<<1)+1)*BH_ + i]);
    a.dcT[(size_t)a.l*BH_ + i] = ldc(&a.cT[i]) + ldc(&a.cT[BH_ + i]);
  }
}
__global__ __launch_bounds__(256,2) void k_enc_persF0(EncArgsO a){
  if(*a.fl) encO_body<1,1>(a); else encO_body<0,1>(a);
}
__global__ __launch_bounds__(256,2) void k_enc_persF12(EncArgsO a){
  if(*a.fl) encO_body<1,4>(a); else encO_body<0,4>(a);
}

struct DecArgsO {
  const int* trg;
  const void* emb; const void* aW; const void* av; const void* pW; const void* pb;
  const void* dWih; const void* dWhh; const void* dbih; const void* dbhh;
  const void* fW; const void* fb;
  const float* Epre; const float* X3;
  float* dh; float* dcT; float* z; float* ctx; float* xp;
  void* out; const int* fl; int* flags; int gbase;
};

template<int BF, int CP>
__device__ __forceinline__ void decO_cell(const DecArgsO& a, float* SM,
    const int l, const int cur, const int jp, const int bh, const int bh_blk,
    const int lane, const int tid, int& g, float& cv){
  constexpr int Kx = CP*256;
  constexpr int HB = (CP==4) ? 2 : 1;
  constexpr int NB = 16/HB;
  const float* xsrc = (l==0) ? (a.xp + (size_t)bh_blk*16*DIN_)
                             : (a.dh + ((size_t)(cur^1)*3 + (l-1))*BH_ + (size_t)bh_blk*16*H_);
  const float* hsrc = a.dh + ((size_t)cur*3 + l)*BH_ + (size_t)bh_blk*16*H_;
  float wx[4][CP*4];
  float wh[4][8];
  #pragma unroll
  for(int gg=0; gg<4; gg++){
    size_t rowx = ((size_t)l*G4_ + (size_t)gg*H_ + jp)*DIN_;
    #pragma unroll
    for(int p=0;p<CP;p++){
      float4 v = LD4<BF>(a.dWih, rowx + (lane<<2) + p*256);
      wx[gg][p*4+0]=v.x; wx[gg][p*4+1]=v.y; wx[gg][p*4+2]=v.z; wx[gg][p*4+3]=v.w;
    }
    size_t rowh = ((size_t)l*G4_ + (size_t)gg*H_ + jp)*H_;
    #pragma unroll
    for(int p=0;p<2;p++){
      float4 v = LD4<BF>(a.dWhh, rowh + (lane<<2) + p*256);
      wh[gg][p*4+0]=v.x; wh[gg][p*4+1]=v.y; wh[gg][p*4+2]=v.z; wh[gg][p*4+3]=v.w;
    }
  }
  float pg[4];
  {
    size_t bb = (size_t)l*G4_ + jp;
    #pragma unroll
    for(int gg=0;gg<4;gg++)
      pg[gg] = LD<BF>(a.dbih, bb + (size_t)gg*H_) + LD<BF>(a.dbhh, bb + (size_t)gg*H_);
  }
  float gv0=0.f,gv1=0.f,gv2=0.f,gv3=0.f;
  #pragma unroll
  for(int hf=0; hf<HB; hf++){
    const float* xg = xsrc + (size_t)hf*NB*Kx;
    const float* hg = hsrc + (size_t)hf*NB*H_;
    #pragma unroll 4
    for(int i=tid; i<NB*Kx; i+=256) SM[i] = ldc(xg + i);
    #pragma unroll 4
    for(int i=tid; i<NB*H_; i+=256) SM[NB*Kx + i] = ldc(hg + i);
    __syncthreads();
    for(int ib2=0; ib2<NB; ib2++){
      const int ib = hf*NB + ib2;
      float gs[4] = {0.f,0.f,0.f,0.f};
      const float* xr = &SM[ib2*Kx + (lane<<2)];
      #pragma unroll
      for(int p=0;p<CP;p++){
        float4 xv = *(const float4*)(xr + p*256);
        float xa[4] = {xv.x,xv.y,xv.z,xv.w};
        #pragma unroll
        for(int gg=0;gg<4;gg++){
          #pragma unroll
          for(int i=0;i<4;i++) gs[gg] = fmaf(xa[i], wx[gg][p*4+i], gs[gg]);
        }
      }
      const float* hr = &SM[NB*Kx + ib2*H_ + (lane<<2)];
      #pragma unroll
      for(int p=0;p<2;p++){
        float4 hv = *(const float4*)(hr + p*256);
        float ha[4] = {hv.x,hv.y,hv.z,hv.w};
        #pragma unroll
        for(int gg=0;gg<4;gg++){
          #pragma unroll
          for(int i=0;i<4;i++) gs[gg] = fmaf(ha[i], wh[gg][p*4+i], gs[gg]);
        }
      }
      #pragma unroll
      for(int gg=0;gg<4;gg++) gs[gg] = bsum(gs[gg]);
      if(lane == ib){ gv0=gs[0]; gv1=gs[1]; gv2=gs[2]; gv3=gs[3]; }
    }
    __syncthreads();
  }
  if(lane < 16){
    const int b = bh*16 + lane;
    float gi = gv0+pg[0], gf = gv1+pg[1], gG = gv2+pg[2], go = gv3+pg[3];
    float c2 = sigm(gf)*cv + sigm(gi)*tanhf(gG);
    float h2 = sigm(go)*tanhf(c2);
    cv = c2;
    stc(&a.dh[((size_t)(cur^1)*3 + l)*BH_ + (size_t)b*H_ + jp], h2);
  }
  gbar(a.flags, ++g);
}

template<int BF>
__device__ void decO_body(const DecArgsO& a){
  __shared__ float SM[16384];
  const int tid  = threadIdx.x;
  const int w    = (blockIdx.x<<2) + (tid>>6);
  const int lane = tid & 63;
  const int jp   = w & 511;
  const int bh   = w >> 9;
  const int bh_blk = blockIdx.x >> 7;
  int g = a.gbase;
  float cvs[3];
  #pragma unroll
  for(int l=0;l<3;l++)
    cvs[l] = a.dcT[((size_t)l*H_ + jp)*32 + (size_t)bh*16 + (lane&15)];
  int cur = 0;
  for(int t=0; t<64; ++t){
    {
      const float* hs = a.dh + ((size_t)cur*3 + 2)*BH_ + (size_t)bh_blk*16*H_;
      #pragma unroll 4
      for(int i=tid; i<16*H_; i+=256) SM[i] = ldc(hs + i);
      __syncthreads();
      if(t < 63){
        float wz[8];
        size_t rz = (size_t)jp*1536;
        #pragma unroll
        for(int p=0;p<2;p++){
          float4 v = LD4<BF>(a.aW, rz + (lane<<2) + p*256);
          wz[p*4+0]=v.x; wz[p*4+1]=v.y; wz[p*4+2]=v.z; wz[p*4+3]=v.w;
        }
        for(int ib=0; ib<16; ib++){
          const float* hp = &SM[(ib<<9) + (lane<<2)];
          float acc = 0.f;
          #pragma unroll
          for(int p=0;p<2;p++){
            float4 hv = *(const float4*)(hp + p*256);
            acc = fmaf(hv.x, wz[p*4+0], acc); acc = fmaf(hv.y, wz[p*4+1], acc);
            acc = fmaf(hv.z, wz[p*4+2], acc); acc = fmaf(hv.w, wz[p*4+3], acc);
          }
          acc = bsum(acc);
          if(lane==0) stc(&a.z[(size_t)(bh*16+ib)*H_ + jp], acc);
        }
      }
      if(t > 0){
        #pragma unroll
        for(int r=0;r<3;r++){
          const int q  = jp + (r<<9);
          const int v_ = q % 96;
          const int ib = q / 96;
          float wf[8];
          size_t rf = (size_t)v_*H_;
          #pragma unroll
          for(int p=0;p<2;p++){
            float4 v = LD4<BF>(a.fW, rf + (lane<<2) + p*256);
            wf[p*4+0]=v.x; wf[p*4+1]=v.y; wf[p*4+2]=v.z; wf[p*4+3]=v.w;
          }
          const float* hp = &SM[(ib<<9) + (lane<<2)];
          float acc = 0.f;
          #pragma unroll
          for(int p=0;p<2;p++){
            float4 hv = *(const float4*)(hp + p*256);
            acc = fmaf(hv.x, wf[p*4+0], acc); acc = fmaf(hv.y, wf[p*4+1], acc);
            acc = fmaf(hv.z, wf[p*4+2], acc); acc = fmaf(hv.w, wf[p*4+3], acc);
          }
          acc = bsum(acc);
          if(lane==0){
            float rr = acc + LD<BF>(a.fb, v_);
            size_t oi = (size_t)(bh*16+ib)*(S_*V_) + (size_t)t*V_ + v_;
            if constexpr(BF) ((u16*)a.out)[oi] = f2b(rr);
            else             ((float*)a.out)[oi] = rr;
          }
        }
      }
    }
    if(t == 63) break;
    gbar(a.flags, ++g);
    if(blockIdx.x < 32){
      const int b = blockIdx.x;
      float* Zs = SM; float* Ss = SM + 512;
      for(int i=tid; i<512; i+=256) Zs[i] = ldc(a.z + (size_t)b*H_ + i);
      __syncthreads();
      float wa[8];
      #pragma unroll
      for(int p=0;p<2;p++){
        float4 v = LD4<BF>(a.av, (lane<<2) + p*256);
        wa[p*4+0]=v.x; wa[p*4+1]=v.y; wa[p*4+2]=v.z; wa[p*4+3]=v.w;
      }
      const int ww = tid>>6;
      for(int s=ww; s<64; s+=4){
        const float* ep = a.Epre + ((size_t)(s*B_ + b))*H_;
        float acc = 0.f;
        #pragma unroll
        for(int p=0;p<2;p++){
          const float4 e4 = *(const float4*)(ep + (lane<<2) + p*256);
          const float4 z4 = *(const float4*)(Zs + (lane<<2) + p*256);
          acc = fmaf(wa[p*4+0], tanhf(e4.x+z4.x), acc);
          acc = fmaf(wa[p*4+1], tanhf(e4.y+z4.y), acc);
          acc = fmaf(wa[p*4+2], tanhf(e4.z+z4.z), acc);
          acc = fmaf(wa[p*4+3], tanhf(e4.w+z4.w), acc);
        }
        acc = bsum(acc);
        if(lane==0) Ss[s] = acc;
      }
      __syncthreads();
      if(tid < 64){
        float vv = Ss[tid];
        float m = vv;
        #pragma unroll
        for(int off=1; off<64; off<<=1) m = fmaxf(m, __shfl_xor(m, off));
        float e = __expf(vv - m);
        float su = e;
        #pragma unroll
        for(int off=1; off<64; off<<=1) su += __shfl_xor(su, off);
        Ss[tid] = e / su;
      }
      __syncthreads();
      for(int d4 = tid<<2; d4 < DIN_; d4 += 1024){
        float a0=0.f,a1=0.f,a2=0.f,a3=0.f;
        const float* xb = a.X3 + (size_t)b*DIN_ + d4;
        for(int s=0;s<64;s++){
          const float pp = Ss[s];
          const float4 xv = *(const float4*)(xb + (size_t)s*BDIN_);
          a0 = fmaf(pp, xv.x, a0); a1 = fmaf(pp, xv.y, a1);
          a2 = fmaf(pp, xv.z, a2); a3 = fmaf(pp, xv.w, a3);
        }
        float* cp = &a.ctx[(size_t)b*DIN_ + d4];
        stc(cp+0, a0); stc(cp+1, a1); stc(cp+2, a2); stc(cp+3, a3);
      }
    }
    gbar(a.flags, ++g);
    {
      const float* cs = a.ctx + (size_t)bh_blk*16*DIN_;
      #pragma unroll 4
      for(int i=tid; i<16*DIN_; i+=256) SM[i] = ldc(cs + i);
      __syncthreads();
      float wpe[2][4], wpc[2][16];
      #pragma unroll
      for(int jj=0;jj<2;jj++){
        size_t row = (size_t)(jp + (jj<<9))*1280;
        float4 v = LD4<BF>(a.pW, row + (lane<<2));
        wpe[jj][0]=v.x; wpe[jj][1]=v.y; wpe[jj][2]=v.z; wpe[jj][3]=v.w;
        #pragma unroll
        for(int p=0;p<4;p++){
          float4 c4 = LD4<BF>(a.pW, row + 256 + (lane<<2) + p*256);
          wpc[jj][p*4+0]=c4.x; wpc[jj][p*4+1]=c4.y; wpc[jj][p*4+2]=c4.z; wpc[jj][p*4+3]=c4.w;
        }
      }
      const float pb0 = LD<BF>(a.pb, jp);
      const float pb1 = LD<BF>(a.pb, jp+512);
      for(int ib=0; ib<16; ib++){
        const int b = bh*16 + ib;
        const int tok = a.trg[b*S_ + t];
        float4 ev = LD4<BF>(a.emb, (size_t)tok*E_ + (lane<<2));
        float ea[4] = {ev.x, ev.y, ev.z, ev.w};
        float s0=0.f, s1=0.f;
        #pragma unroll
        for(int i=0;i<4;i++){ s0 = fmaf(ea[i], wpe[0][i], s0); s1 = fmaf(ea[i], wpe[1][i], s1); }
        const float* cp = &SM[(ib<<10) + (lane<<2)];
        #pragma unroll
        for(int p=0;p<4;p++){
          float4 c4 = *(const float4*)(cp + p*256);
          float ca[4] = {c4.x,c4.y,c4.z,c4.w};
          #pragma unroll
          for(int i=0;i<4;i++){ s0 = fmaf(ca[i], wpc[0][p*4+i], s0); s1 = fmaf(ca[i], wpc[1][p*4+i], s1); }
        }
        s0 = bsum(s0); s1 = bsum(s1);
        if(lane==0){
          stc(&a.xp[(size_t)b*DIN_ + jp],       s0 + pb0);
          stc(&a.xp[(size_t)b*DIN_ + jp + 512], s1 + pb1);
        }
      }
    }
    gbar(a.flags, ++g);
    decO_cell<BF,4>(a, SM, 0, cur, jp, bh, bh_blk, lane, tid, g, cvs[0]);
    decO_cell<BF,2>(a, SM, 1, cur, jp, bh, bh_blk, lane, tid, g, cvs[1]);
    decO_cell<BF,2>(a, SM, 2, cur, jp, bh, bh_blk, lane, tid, g, cvs[2]);
    cur ^= 1;
  }
}
__global__ __launch_bounds__(256,2) void k_dec_persO(DecArgsO a){
  if(*a.fl) decO_body<1>(a); else decO_body<0>(a);
}

// ---------------------------------------------------------------------------
extern "C" void kernel_launch(void* const* d_in, const int* in_sizes, int n_in,
                              void* d_out, int out_size, void* d_ws, size_t ws_size,
                              hipStream_t stream){
  const int* src  = (const int*)d_in[0];
  const int* trg  = (const int*)d_in[1];
  const void* emb = d_in[2];
  const void* eWih= d_in[3];
  const void* eWhh= d_in[4];
  const void* ebih= d_in[5];
  const void* ebhh= d_in[6];
  const void* dWih= d_in[7];
  const void* dWhh= d_in[8];
  const void* dbih= d_in[9];
  const void* dbhh= d_in[10];
  const void* aW  = d_in[11];
  const void* ab  = d_in[12];
  const void* av  = d_in[13];
  const void* pW  = d_in[14];
  const void* pb  = d_in[15];
  const void* fW  = d_in[16];
  const void* fb  = d_in[17];

  char* base = (char*)d_ws;
  size_t off = 0;
  auto take = [&](size_t bytes)->char*{
    char* p = base + off; off = (off + bytes + 255) & ~(size_t)255; return p;
  };

  const size_t szX  = (size_t)2048*1024*4;   // 8 MB
  const size_t szG  = (size_t)2048*4096*4;   // 32 MB
  const size_t szE  = (size_t)2048*512*4;    // 4 MB
  int planA = ws_size >= (size_t)53*1024*1024;

  if(planA){
    float* X    = (float*)take(szX);               // Xin/Xout in-place
    float* Xh   = (float*)take(szX);               // henc: 64 slots * 2 * BH * 4 = 8 MB
    float* G    = (float*)take(szG);
    // decoder t-indexed buffers overlay G (dead after encoder):
    float* dhb  = G;                               // 64*3*BH f = 12.6 MB
    float* xpb  = dhb + (size_t)64*3*BH_;          // 63*B*DIN f = 8.3 MB (<= 32)
    float* Epre = (float*)take(szE);
    float* cTe  = (float*)take((size_t)2*BH_*4);
    float* dh0  = (float*)take((size_t)3*BH_*4);
    float* dcT  = (float*)take((size_t)3*BH_*4);
    int* fl     = (int*)take(256);
    int* flags  = (int*)take((256*FSTRIDE + 16)*4);

    k_detect<<<1, 256, 0, stream>>>(av, fl, flags);
    k_embed<<<8192, 256, 0, stream>>>(src, emb, X, fl);

    for(int l=0;l<L_;l++){
      int K = (l==0) ? E_ : DIN_;
      k_gemm<<<dim3(64,16), 256, 0, stream>>>(X, DIN_,
          eWih, DIN_, (size_t)l*2*G4_*DIN_,
          ebih, (size_t)l*2*G4_, ebhh, (size_t)l*2*G4_,
          G, 4096, K, fl);
      EncArgs2 ea;
      ea.G = G; ea.Whh = eWhh; ea.oWh = (size_t)l*2*G4_*H_;
      ea.henc = Xh; ea.cT = cTe; ea.Xout = X;
      ea.dh0 = dh0; ea.dcT = dcT; ea.l = l;
      ea.fl = fl; ea.flags = flags; ea.gbase = l*65;
      k_enc2<<<256, 512, 0, stream>>>(ea);
    }
    k_gemm<<<dim3(8,16), 256, 0, stream>>>(X, DIN_,
        aW, 3*H_, (size_t)H_, ab, 0, nullptr, 0, Epre, H_, DIN_, fl);
    k_outzero<<<12, 256, 0, stream>>>(d_out, fl);

    DecArgs2 da;
    da.trg = trg; da.emb = emb; da.aW = aW; da.av = av; da.pW = pW; da.pb = pb;
    da.dWih = dWih; da.dWhh = dWhh; da.dbih = dbih; da.dbhh = dbhh;
    da.fW = fW; da.fb = fb;
    da.Epre = Epre; da.X3 = X;
    da.dh0 = dh0; da.dhb = dhb; da.xpb = xpb;
    da.dcT = dcT; da.out = d_out; da.fl = fl; da.flags = flags; da.gbase = 3*65;
    k_dec2<<<256, 512, 0, stream>>>(da);
  } else {
    // -------- fallback: round-4 proven path (fused encoder + ldc decoder) --------
    float* XA   = (float*)take(szX);
    float* XB   = (float*)take(szX);
    float* Epre = (float*)take(szE);
    float* hst  = (float*)take((size_t)4*BH_*4);
    float* cTe  = (float*)take((size_t)2*BH_*4);
    float* dh   = (float*)take((size_t)6*BH_*4);
    float* dcT  = (float*)take((size_t)3*BH_*4);
    float* zbuf = (float*)take((size_t)BH_*4);
    float* ctx  = (float*)take((size_t)2*BH_*4);
    float* xp   = (float*)take((size_t)2*BH_*4);
    int* fl     = (int*)take(256);
    int* flags  = (int*)take((256*FSTRIDE + 16)*4);

    k_detect<<<1, 256, 0, stream>>>(av, fl, flags);
    k_embed<<<8192, 256, 0, stream>>>(src, emb, XA, fl);

    float* Xin = XA; float* Xout = XB;
    for(int l=0;l<L_;l++){
      EncArgsO ea;
      ea.G = nullptr; ea.Xin = Xin;
      ea.Wih = eWih; ea.oWi = (size_t)l*2*G4_*DIN_;
      ea.Whh = eWhh; ea.oWh = (size_t)l*2*G4_*H_;
      ea.bih = ebih; ea.obi = (size_t)l*2*G4_;
      ea.bhh = ebhh; ea.obh = (size_t)l*2*G4_;
      ea.hst = hst; ea.cT = cTe; ea.Xout = Xout;
      ea.dh = dh; ea.dcT = dcT; ea.l = l;
      ea.fl = fl; ea.flags = flags; ea.gbase = l*65;
      if(l == 0) k_enc_persF0<<<256, 256, 0, stream>>>(ea);
      else       k_enc_persF12<<<256, 256, 0, stream>>>(ea);
      float* tmp = Xin; Xin = Xout; Xout = tmp;
    }
    k_gemm<<<dim3(8,16), 256, 0, stream>>>(Xin, DIN_,
        aW, 3*H_, (size_t)H_, ab, 0, nullptr, 0, Epre, H_, DIN_, fl);
    k_outzero<<<12, 256, 0, stream>>>(d_out, fl);

    DecArgsO da;
    da.trg = trg; da.emb = emb; da.aW = aW; da.av = av; da.pW = pW; da.pb = pb;
    da.dWih = dWih; da.dWhh = dWhh; da.dbih = dbih; da.dbhh = dbhh;
    da.fW = fW; da.fb = fb;
    da.Epre = Epre; da.X3 = Xin;
    da.dh = dh; da.dcT = dcT; da.z = zbuf; da.ctx = ctx; da.xp = xp;
    da.out = d_out; da.fl = fl; da.flags = flags; da.gbase = 3*65;
    k_dec_persO<<<256, 256, 0, stream>>>(da);
  }
}

// Round 10
// 9583.755 us; speedup vs baseline: 2.1339x; 2.1339x over previous
//
#include <hip/hip_runtime.h>

#define B_ 32
#define S_ 64
#define V_ 96
#define E_ 256
#define H_ 512
#define L_ 3
#define DIN_ 1024
#define G4_ 2048
#define BH_ (B_*H_)
#define BDIN_ (B_*DIN_)
#define FSTRIDE 16   // flags spaced 64B apart

typedef unsigned short u16;

__device__ __forceinline__ float bfu(u16 u){ return __uint_as_float(((unsigned)u) << 16); }
__device__ __forceinline__ u16 f2b(float f){           // RNE float->bf16
  unsigned x = __float_as_uint(f);
  unsigned r = (x + 0x7FFFu + ((x >> 16) & 1u)) >> 16;
  return (u16)r;
}
__device__ __forceinline__ float sigm(float x){ return 1.f/(1.f+__expf(-x)); }
__device__ __forceinline__ float bsum(float a){
  #pragma unroll
  for(int off=1; off<64; off<<=1) a += __shfl_xor(a, off);
  return a;
}
// Coherent (LLC-point) access: relaxed agent-scope atomics emit sc0/sc1
// load/store -- per-access coherence, NO cache wb/inv instructions.
__device__ __forceinline__ void stc(float* p, float v){
  __hip_atomic_store(p, v, __ATOMIC_RELAXED, __HIP_MEMORY_SCOPE_AGENT);
}
__device__ __forceinline__ float ldc(const float* p){
  return __hip_atomic_load((float*)p, __ATOMIC_RELAXED, __HIP_MEMORY_SCOPE_AGENT);
}
__device__ __forceinline__ void stci(int* p, int v){
  __hip_atomic_store(p, v, __ATOMIC_RELAXED, __HIP_MEMORY_SCOPE_AGENT);
}
__device__ __forceinline__ int ldci(const int* p){
  return __hip_atomic_load((int*)p, __ATOMIC_RELAXED, __HIP_MEMORY_SCOPE_AGENT);
}
// Dual-dtype INPUT loads. BF=1: buffer is bf16 (u16); BF=0: buffer is fp32.
template<int BF> __device__ __forceinline__ float LD(const void* p, size_t i){
  if constexpr(BF) return bfu(((const u16*)p)[i]);
  else             return ((const float*)p)[i];
}
template<int BF> __device__ __forceinline__ float4 LD4(const void* p, size_t i){
  if constexpr(BF){
    const u16* q = (const u16*)p + i;
    ushort4 w = *(const ushort4*)q;
    return make_float4(bfu(w.x), bfu(w.y), bfu(w.z), bfu(w.w));
  } else {
    return *(const float4*)((const float*)p + i);
  }
}

// ---------------------------------------------------------------------------
// Distributed contention-free grid barrier (round-4 proven).
__device__ __forceinline__ void gbar(int* flags, int g){
  __syncthreads();
  if(threadIdx.x < 64){
    if(threadIdx.x == 0) stci(&flags[blockIdx.x*FSTRIDE], g);
    const int i0 = threadIdx.x*4;
    for(;;){
      int f0 = ldci(&flags[(i0+0)*FSTRIDE]);
      int f1 = ldci(&flags[(i0+1)*FSTRIDE]);
      int f2 = ldci(&flags[(i0+2)*FSTRIDE]);
      int f3 = ldci(&flags[(i0+3)*FSTRIDE]);
      bool ok = (f0>=g) && (f1>=g) && (f2>=g) && (f3>=g);
      if(__all(ok)) break;
      __builtin_amdgcn_s_sleep(1);
    }
  }
  __syncthreads();
}

// ---------------------------------------------------------------------------
__global__ void k_detect(const void* av, int* flag, int* flags){
  __shared__ int cnt;
  if(threadIdx.x == 0) cnt = 0;
  __syncthreads();
  u16 w = ((const u16*)av)[2*threadIdx.x];
  if(w & 0x8000) atomicAdd(&cnt, 1);
  __syncthreads();
  for(int i=threadIdx.x; i<256*FSTRIDE+16; i+=256) flags[i] = 0;
  if(threadIdx.x == 0) *flag = (cnt <= 8) ? 1 : 0;   // 1 = bf16 inputs
}

// ---------------------------------------------------------------------------
template<int BF> __device__ void embed_body(const int* __restrict__ src,
                                            const void* __restrict__ emb,
                                            float* __restrict__ X0){
  int idx = blockIdx.x*256 + threadIdx.x;   // exactly S*B*DIN threads
  int d  = idx & (DIN_-1);
  int sb = idx >> 10;
  int b  = sb & (B_-1);
  int s  = sb >> 5;
  float v = 0.f;
  if(d < E_){
    int tok = src[b*S_ + s];
    v = LD<BF>(emb, (size_t)tok*E_ + d);
  }
  X0[idx] = v;
}
__global__ void k_embed(const int* src, const void* emb, float* X0, const int* fl){
  if(*fl) embed_body<1>(src, emb, X0); else embed_body<0>(src, emb, X0);
}

// ---------------------------------------------------------------------------
// Tiled GEMM: C[m,n] = sum_k A[m*lda+k] * W[woff + n*ldw + k] + b1[n] + b2[n]
template<int BF> __device__ void gemm_body(
  const float* __restrict__ A, int lda,
  const void* __restrict__ W, int ldw, size_t woff,
  const void* __restrict__ b1, size_t o1,
  const void* __restrict__ b2, size_t o2,
  float* __restrict__ C, int ldc, int K)
{
  __shared__ float As[16][128];
  __shared__ float Bs[16][64];
  const int tid = threadIdx.x;
  const int m0 = blockIdx.y * 128;
  const int n0 = blockIdx.x * 64;
  const int tx = tid & 15, ty = tid >> 4;
  const int amm = tid & 127, akk = (tid >> 7) * 8;
  const int bnn = tid >> 2,  bkk = (tid & 3) * 4;
  float acc[8][4] = {{0.f}};
  for(int k0 = 0; k0 < K; k0 += 16){
    const float4* ap = (const float4*)(A + (size_t)(m0+amm)*lda + (k0 + akk));
    float4 a0 = ap[0];
    float4 a1 = ap[1];
    float4 wv = LD4<BF>(W, woff + (size_t)(n0+bnn)*ldw + (k0 + bkk));
    As[akk+0][amm]=a0.x; As[akk+1][amm]=a0.y; As[akk+2][amm]=a0.z; As[akk+3][amm]=a0.w;
    As[akk+4][amm]=a1.x; As[akk+5][amm]=a1.y; As[akk+6][amm]=a1.z; As[akk+7][amm]=a1.w;
    Bs[bkk+0][bnn]=wv.x; Bs[bkk+1][bnn]=wv.y;
    Bs[bkk+2][bnn]=wv.z; Bs[bkk+3][bnn]=wv.w;
    __syncthreads();
    #pragma unroll
    for(int kk=0;kk<16;kk++){
      const float4 av0 = *(const float4*)&As[kk][ty*8];
      const float4 av1 = *(const float4*)&As[kk][ty*8+4];
      const float4 bv  = *(const float4*)&Bs[kk][tx*4];
      float am[8] = {av0.x,av0.y,av0.z,av0.w,av1.x,av1.y,av1.z,av1.w};
      float bn[4] = {bv.x,bv.y,bv.z,bv.w};
      #pragma unroll
      for(int i=0;i<8;i++){
        #pragma unroll
        for(int j=0;j<4;j++) acc[i][j] = fmaf(am[i], bn[j], acc[i][j]);
      }
    }
    __syncthreads();
  }
  float bias[4];
  #pragma unroll
  for(int j=0;j<4;j++){
    float bb = 0.f;
    if(b1) bb += LD<BF>(b1, o1 + n0 + tx*4 + j);
    if(b2) bb += LD<BF>(b2, o2 + n0 + tx*4 + j);
    bias[j] = bb;
  }
  #pragma unroll
  for(int i=0;i<8;i++){
    float* cp = C + (size_t)(m0 + ty*8 + i)*ldc + (n0 + tx*4);
    #pragma unroll
    for(int j=0;j<4;j++) cp[j] = acc[i][j] + bias[j];
  }
}
__global__ __launch_bounds__(256) void k_gemm(
  const float* A, int lda, const void* W, int ldw, size_t woff,
  const void* b1, size_t o1, const void* b2, size_t o2,
  float* C, int ldc, int K, const int* fl)
{
  if(*fl) gemm_body<1>(A,lda,W,ldw,woff,b1,o1,b2,o2,C,ldc,K);
  else    gemm_body<0>(A,lda,W,ldw,woff,b1,o1,b2,o2,C,ldc,K);
}

// ---------------------------------------------------------------------------
__global__ void k_outzero(void* __restrict__ out, const int* fl){
  int i = blockIdx.x*256 + threadIdx.x;
  if(i < B_*V_){
    int b = i / V_, v = i % V_;
    size_t idx = (size_t)b*(S_*V_) + v;
    if(*fl) ((u16*)out)[idx] = 0;
    else    ((float*)out)[idx] = 0.f;
  }
}

// ===========================================================================
// ENCODER (round-8 proven, unchanged): 512-thread wave-pair persistent kernel.
// ===========================================================================
struct EncArgs2 {
  const float* G;
  const void* Whh; size_t oWh;
  float* henc;   // [64 gen-slots][2 dir][BH] fp32  (slot = gen & 63)
  float* cT;     // [2 dir][j*32+b] coherent
  float* Xout;   // [(t*B+b)][DIN]
  float* dh0;    // decoder h init [3][BH]
  float* dcT;    // decoder c init [3][j*32+b]
  int l;
  const int* fl;
  int* flags; int gbase;
};

template<int BF>
__device__ void enc2_body(const EncArgs2& a){
  __shared__ float SM[16384];
  const int tid  = threadIdx.x;
  const int lane = tid & 63;
  const int wid  = tid >> 6;                 // 0..7
  const int w4   = (blockIdx.x<<2) + (wid & 3);
  const int j    = w4 & 511;
  const int d    = w4 >> 9;
  const int half = wid >> 2;                 // wave-pair half
  int g = a.gbase;

  float wh[4][8];
  #pragma unroll
  for(int gg=0; gg<4; gg++){
    size_t rowh = a.oWh + ((size_t)d*G4_ + (size_t)gg*H_ + j)*H_;
    #pragma unroll
    for(int p=0;p<2;p++){
      float4 v = LD4<BF>(a.Whh, rowh + (lane<<2) + p*256);
      wh[gg][p*4+0]=v.x; wh[gg][p*4+1]=v.y; wh[gg][p*4+2]=v.z; wh[gg][p*4+3]=v.w;
    }
  }
  const bool own = (lane < 32) && ((lane>>4) == half);   // this wave's batches
  const size_t ci = ((size_t)d*H_ + j)*32 + (lane & 31);
  float cv = 0.f;

  for(int p=0;p<64;p++){
    const int t = d ? (63-p) : p;
    if(p == 0){
      for(int i=tid<<2; i<BH_; i+=2048) *(float4*)&SM[i] = make_float4(0.f,0.f,0.f,0.f);
    } else {
      const float* hsrc = a.henc + (size_t)((p&63)*2 + d)*BH_;  // slot p, fresh
      for(int i=tid<<2; i<BH_; i+=2048) *(float4*)&SM[i] = *(const float4*)&hsrc[i];
    }
    __syncthreads();

    const int bE = lane & 31;
    const float* Gp = a.G + (size_t)(t*B_+bE)*4096 + (size_t)d*G4_ + j;
    float pg0=Gp[0], pg1=Gp[512], pg2=Gp[1024], pg3=Gp[1536];

    float gv0=0.f, gv1=0.f, gv2=0.f, gv3=0.f;
    for(int b=half*16; b<half*16+16; b++){
      float gs[4] = {0.f,0.f,0.f,0.f};
      const float* hp = &SM[(b<<9) + (lane<<2)];
      #pragma unroll
      for(int pp=0;pp<2;pp++){
        float4 hv = *(const float4*)(hp + pp*256);
        float ha[4] = {hv.x,hv.y,hv.z,hv.w};
        #pragma unroll
        for(int gg=0;gg<4;gg++){
          #pragma unroll
          for(int i=0;i<4;i++) gs[gg] = fmaf(ha[i], wh[gg][pp*4+i], gs[gg]);
        }
      }
      #pragma unroll
      for(int gg=0;gg<4;gg++) gs[gg] = bsum(gs[gg]);
      if(lane == b){ gv0=gs[0]; gv1=gs[1]; gv2=gs[2]; gv3=gs[3]; }
    }
    if(own){
      float gi = gv0+pg0, gf = gv1+pg1, gG = gv2+pg2, go = gv3+pg3;
      float c2 = sigm(gf)*cv + sigm(gi)*tanhf(gG);
      float h2 = sigm(go)*tanhf(c2);
      cv = c2;
      stc(&a.henc[(size_t)(((p+1)&63)*2 + d)*BH_ + (size_t)lane*H_ + j], h2);
      a.Xout[(size_t)(t*B_+lane)*DIN_ + (d<<9) + j] = h2;
    }
    gbar(a.flags, ++g);
  }
  if(own) stc(&a.cT[ci], cv);
  gbar(a.flags, ++g);
  for(int i = blockIdx.x*512 + tid; i < BH_; i += 131072){
    float hf2 = a.henc[(size_t)(0*2+0)*BH_ + i];
    float hb2 = a.henc[(size_t)(0*2+1)*BH_ + i];
    a.dh0[(size_t)a.l*BH_ + i] = hf2 + hb2;
    a.dcT[(size_t)a.l*BH_ + i] = ldc(&a.cT[i]) + ldc(&a.cT[BH_ + i]);
  }
}
__global__ __launch_bounds__(512,1) void k_enc2(EncArgs2 a){
  if(*a.fl) enc2_body<1>(a); else enc2_body<0>(a);
}

// ===========================================================================
// DECODER (plan A6): R8 phase structure (Z|ATT|PROJ|c0|c1|c2), but cells use
// GATE-SPLIT wave pairs: wave half computes gates {2*half, 2*half+1} for ALL
// 16 batches over full K.  Each wave loads only its 2 gates' weight rows =>
// zero duplicate weight fetches (vs R8's batch-split).  Partials combined
// through LDS; gate math + state store on half-0 lanes.  Cell weights are
// prefetched into registers BEFORE the preceding gbar (latency hides under
// barrier wait).
// ===========================================================================
struct DecArgs2 {
  const int* trg;
  const void* emb; const void* aW; const void* av; const void* pW; const void* pb;
  const void* dWih; const void* dWhh; const void* dbih; const void* dbhh;
  const void* fW; const void* fb;
  const float* Epre; const float* X3;
  const float* dh0;   // [3][BH] initial h (from encoder)
  float* dhb;   // [64 t-slots][3][BH] fp32 (slot t = state entering step t)
  float* zb;    // [63][B][H] fp32
  u16*   ctxb;  // [63][B][DIN] bf16
  float* xpb;   // [63][B][DIN] fp32
  const float* dcT;  // [3][j*32+b]
  void* out;
  const int* fl;
  int* flags; int gbase;
};

// Load this wave's 2 gates' weights (gates 2*half, 2*half+1).
template<int BF, int CP>
__device__ __forceinline__ void dec_loadW(const DecArgs2& a, const int l,
    const int jp, const int lane, const int half,
    float wx[2][16], float wh[2][8], float pg[2]){
  #pragma unroll
  for(int gg=0; gg<2; gg++){
    const int gr = half*2 + gg;
    size_t rowx = ((size_t)l*G4_ + (size_t)gr*H_ + jp)*DIN_;
    #pragma unroll
    for(int p=0;p<CP;p++){
      float4 v = LD4<BF>(a.dWih, rowx + (lane<<2) + p*256);
      wx[gg][p*4+0]=v.x; wx[gg][p*4+1]=v.y; wx[gg][p*4+2]=v.z; wx[gg][p*4+3]=v.w;
    }
    size_t rowh = ((size_t)l*G4_ + (size_t)gr*H_ + jp)*H_;
    #pragma unroll
    for(int p=0;p<2;p++){
      float4 v = LD4<BF>(a.dWhh, rowh + (lane<<2) + p*256);
      wh[gg][p*4+0]=v.x; wh[gg][p*4+1]=v.y; wh[gg][p*4+2]=v.z; wh[gg][p*4+3]=v.w;
    }
    size_t bb = (size_t)l*G4_ + (size_t)gr*H_ + jp;
    pg[gg] = LD<BF>(a.dbih, bb) + LD<BF>(a.dbhh, bb);
  }
}

template<int BF, int CP>   // Kx = CP*256
__device__ __forceinline__ void dec_cellG(const DecArgs2& a, float* SM,
    const int t, const int l, const int jp, const int bh, const int bh_blk,
    const int lane, const int tid, const int half, const int pairid,
    float wx[2][16], float wh[2][8], float pg[2], float& cv){
  constexpr int Kx  = CP*256;
  constexpr int HB  = (CP==4) ? 2 : 1;
  constexpr int NBs = 16/HB;       // batches staged per hf
  const float* xsrc = (l==0) ? (a.xpb + (size_t)t*BDIN_ + (size_t)bh_blk*16*DIN_)
                             : (a.dhb + (size_t)((t+1)*3 + (l-1))*BH_ + (size_t)bh_blk*16*H_);
  const float* hsrc = (t==0) ? (a.dh0 + (size_t)l*BH_ + (size_t)bh_blk*16*H_)
                             : (a.dhb + (size_t)(t*3 + l)*BH_ + (size_t)bh_blk*16*H_);
  float gvA=0.f, gvB=0.f;   // this wave's 2 gate partials (lane ib holds batch ib)
  #pragma unroll
  for(int hf=0; hf<HB; hf++){
    const float* xg = xsrc + (size_t)hf*NBs*Kx;
    const float* hg = hsrc + (size_t)hf*NBs*H_;
    for(int i=tid<<2; i<NBs*Kx; i+=2048) *(float4*)&SM[i] = *(const float4*)&xg[i];
    for(int i=tid<<2; i<NBs*H_; i+=2048) *(float4*)&SM[NBs*Kx + i] = *(const float4*)&hg[i];
    __syncthreads();
    for(int ib2=0; ib2<NBs; ib2++){
      const int ib = hf*NBs + ib2;
      float gs0=0.f, gs1=0.f;
      const float* xr = &SM[ib2*Kx + (lane<<2)];
      #pragma unroll
      for(int p=0;p<CP;p++){
        float4 xv = *(const float4*)(xr + p*256);
        gs0 = fmaf(xv.x, wx[0][p*4+0], gs0); gs0 = fmaf(xv.y, wx[0][p*4+1], gs0);
        gs0 = fmaf(xv.z, wx[0][p*4+2], gs0); gs0 = fmaf(xv.w, wx[0][p*4+3], gs0);
        gs1 = fmaf(xv.x, wx[1][p*4+0], gs1); gs1 = fmaf(xv.y, wx[1][p*4+1], gs1);
        gs1 = fmaf(xv.z, wx[1][p*4+2], gs1); gs1 = fmaf(xv.w, wx[1][p*4+3], gs1);
      }
      const float* hr = &SM[NBs*Kx + ib2*H_ + (lane<<2)];
      #pragma unroll
      for(int p=0;p<2;p++){
        float4 hv = *(const float4*)(hr + p*256);
        gs0 = fmaf(hv.x, wh[0][p*4+0], gs0); gs0 = fmaf(hv.y, wh[0][p*4+1], gs0);
        gs0 = fmaf(hv.z, wh[0][p*4+2], gs0); gs0 = fmaf(hv.w, wh[0][p*4+3], gs0);
        gs1 = fmaf(hv.x, wh[1][p*4+0], gs1); gs1 = fmaf(hv.y, wh[1][p*4+1], gs1);
        gs1 = fmaf(hv.z, wh[1][p*4+2], gs1); gs1 = fmaf(hv.w, wh[1][p*4+3], gs1);
      }
      gs0 = bsum(gs0); gs1 = bsum(gs1);
      if(lane == ib){ gvA=gs0; gvB=gs1; }
    }
    __syncthreads();   // staging region dead after this
  }
  // combine across the pair through LDS: comb[pair][half][16][2]
  float* comb = SM + 15360 + pairid*128;
  if(lane < 16){
    comb[half*32 + lane*2 + 0] = gvA + pg[0];
    comb[half*32 + lane*2 + 1] = gvB + pg[1];
  }
  __syncthreads();
  if(half == 0 && lane < 16){
    const int b = bh*16 + lane;
    float gi = comb[lane*2 + 0];
    float gf = comb[lane*2 + 1];
    float gG = comb[32 + lane*2 + 0];
    float go = comb[32 + lane*2 + 1];
    float c2 = sigm(gf)*cv + sigm(gi)*tanhf(gG);
    float h2 = sigm(go)*tanhf(c2);
    cv = c2;
    stc(&a.dhb[(size_t)((t+1)*3 + l)*BH_ + (size_t)b*H_ + jp], h2);
  }
}

template<int BF>
__device__ void dec2_body(const DecArgs2& a){
  __shared__ float SM[16384];
  const int tid  = threadIdx.x;
  const int lane = tid & 63;
  const int wid  = tid >> 6;                 // 0..7
  const int w4   = (blockIdx.x<<2) + (wid & 3);
  const int jp   = w4 & 511;
  const int bh   = w4 >> 9;
  const int half = wid >> 2;
  const int pairid = wid & 3;
  const int bh_blk = blockIdx.x >> 7;
  int g = a.gbase;

  float cvs[3];
  #pragma unroll
  for(int l=0;l<3;l++)
    cvs[l] = a.dcT[((size_t)l*H_ + jp)*32 + (size_t)bh*16 + (lane&15)];

  float wx[2][16], wh[2][8], pg[2];

  for(int t=0; t<64; ++t){
    // ---- Phase Z: z(t) from htop(t), fc(t-1) from same htop ----
    {
      const float* hs = (t==0) ? (a.dh0 + (size_t)2*BH_ + (size_t)bh_blk*16*H_)
                               : (a.dhb + (size_t)(t*3 + 2)*BH_ + (size_t)bh_blk*16*H_);
      for(int i=tid<<2; i<16*H_; i+=2048) *(float4*)&SM[i] = *(const float4*)&hs[i];
      __syncthreads();
      if(t < 63){
        float wz[8];
        size_t rz = (size_t)jp*1536;
        #pragma unroll
        for(int p=0;p<2;p++){
          float4 v = LD4<BF>(a.aW, rz + (lane<<2) + p*256);
          wz[p*4+0]=v.x; wz[p*4+1]=v.y; wz[p*4+2]=v.z; wz[p*4+3]=v.w;
        }
        for(int ib=half*8; ib<half*8+8; ib++){
          const float* hp = &SM[(ib<<9) + (lane<<2)];
          float acc = 0.f;
          #pragma unroll
          for(int p=0;p<2;p++){
            float4 hv = *(const float4*)(hp + p*256);
            acc = fmaf(hv.x, wz[p*4+0], acc); acc = fmaf(hv.y, wz[p*4+1], acc);
            acc = fmaf(hv.z, wz[p*4+2], acc); acc = fmaf(hv.w, wz[p*4+3], acc);
          }
          acc = bsum(acc);
          if(lane==0) stc(&a.zb[(size_t)t*BH_ + (size_t)(bh*16+ib)*H_ + jp], acc);
        }
      }
      if(t > 0){
        #pragma unroll
        for(int r=0;r<3;r++){
          const int q  = jp + (r<<9);
          const int v_ = q % 96;
          const int ib = q / 96;
          if((ib>>3) != half) continue;       // each output by exactly one wave
          float wf[8];
          size_t rf = (size_t)v_*H_;
          #pragma unroll
          for(int p=0;p<2;p++){
            float4 v = LD4<BF>(a.fW, rf + (lane<<2) + p*256);
            wf[p*4+0]=v.x; wf[p*4+1]=v.y; wf[p*4+2]=v.z; wf[p*4+3]=v.w;
          }
          const float* hp = &SM[(ib<<9) + (lane<<2)];
          float acc = 0.f;
          #pragma unroll
          for(int p=0;p<2;p++){
            float4 hv = *(const float4*)(hp + p*256);
            acc = fmaf(hv.x, wf[p*4+0], acc); acc = fmaf(hv.y, wf[p*4+1], acc);
            acc = fmaf(hv.z, wf[p*4+2], acc); acc = fmaf(hv.w, wf[p*4+3], acc);
          }
          acc = bsum(acc);
          if(lane==0){
            float rr = acc + LD<BF>(a.fb, v_);
            size_t oi = (size_t)(bh*16+ib)*(S_*V_) + (size_t)t*V_ + v_;
            if constexpr(BF) ((u16*)a.out)[oi] = f2b(rr);
            else             ((float*)a.out)[oi] = rr;
          }
        }
      }
    }
    if(t == 63) break;
    gbar(a.flags, ++g);

    // ---- Phase ATT: blocks 0..31 own batch b ----
    if(blockIdx.x < 32){
      const int b = blockIdx.x;
      float* Zs = SM; float* Ss = SM + 512;
      for(int i=tid; i<512; i+=512) Zs[i] = a.zb[(size_t)t*BH_ + (size_t)b*H_ + i];
      __syncthreads();
      float wa[8];
      #pragma unroll
      for(int p=0;p<2;p++){
        float4 v = LD4<BF>(a.av, (lane<<2) + p*256);
        wa[p*4+0]=v.x; wa[p*4+1]=v.y; wa[p*4+2]=v.z; wa[p*4+3]=v.w;
      }
      for(int s=wid; s<64; s+=8){
        const float* ep = a.Epre + ((size_t)(s*B_ + b))*H_;
        float acc = 0.f;
        #pragma unroll
        for(int p=0;p<2;p++){
          const float4 e4 = *(const float4*)(ep + (lane<<2) + p*256);
          const float4 z4 = *(const float4*)(Zs + (lane<<2) + p*256);
          acc = fmaf(wa[p*4+0], tanhf(e4.x+z4.x), acc);
          acc = fmaf(wa[p*4+1], tanhf(e4.y+z4.y), acc);
          acc = fmaf(wa[p*4+2], tanhf(e4.z+z4.z), acc);
          acc = fmaf(wa[p*4+3], tanhf(e4.w+z4.w), acc);
        }
        acc = bsum(acc);
        if(lane==0) Ss[s] = acc;
      }
      __syncthreads();
      if(tid < 64){
        float vv = Ss[tid];
        float m = vv;
        #pragma unroll
        for(int off=1; off<64; off<<=1) m = fmaxf(m, __shfl_xor(m, off));
        float e = __expf(vv - m);
        float su = e;
        #pragma unroll
        for(int off=1; off<64; off<<=1) su += __shfl_xor(su, off);
        Ss[tid] = e / su;
      }
      __syncthreads();
      for(int d4 = tid<<2; d4 < DIN_; d4 += 2048){
        float a0=0.f,a1=0.f,a2=0.f,a3=0.f;
        const float* xb = a.X3 + (size_t)b*DIN_ + d4;
        for(int s=0;s<64;s++){
          const float pp = Ss[s];
          const float4 xv = *(const float4*)(xb + (size_t)s*BDIN_);
          a0 = fmaf(pp, xv.x, a0); a1 = fmaf(pp, xv.y, a1);
          a2 = fmaf(pp, xv.z, a2); a3 = fmaf(pp, xv.w, a3);
        }
        u16* cp = a.ctxb + (size_t)t*BDIN_ + (size_t)b*DIN_ + d4;
        unsigned lo = (unsigned)f2b(a0) | ((unsigned)f2b(a1)<<16);
        unsigned hi = (unsigned)f2b(a2) | ((unsigned)f2b(a3)<<16);
        stci((int*)cp, (int)lo);
        stci(((int*)cp)+1, (int)hi);
      }
    }
    gbar(a.flags, ++g);

    // ---- Phase PROJ ----
    {
      const u16* cs = a.ctxb + (size_t)t*BDIN_ + (size_t)bh_blk*16*DIN_;
      for(int i=tid*4; i<16*DIN_; i+=2048){          // conflict-free unpack
        ushort4 v = *(const ushort4*)(cs + i);
        *(float4*)&SM[i] = make_float4(bfu(v.x), bfu(v.y), bfu(v.z), bfu(v.w));
      }
      __syncthreads();
      float wpe[2][4], wpc[2][16];
      #pragma unroll
      for(int jj=0;jj<2;jj++){
        size_t row = (size_t)(jp + (jj<<9))*1280;
        float4 v = LD4<BF>(a.pW, row + (lane<<2));
        wpe[jj][0]=v.x; wpe[jj][1]=v.y; wpe[jj][2]=v.z; wpe[jj][3]=v.w;
        #pragma unroll
        for(int p=0;p<4;p++){
          float4 c4 = LD4<BF>(a.pW, row + 256 + (lane<<2) + p*256);
          wpc[jj][p*4+0]=c4.x; wpc[jj][p*4+1]=c4.y; wpc[jj][p*4+2]=c4.z; wpc[jj][p*4+3]=c4.w;
        }
      }
      const float pb0 = LD<BF>(a.pb, jp);
      const float pb1 = LD<BF>(a.pb, jp+512);
      for(int ib=half*8; ib<half*8+8; ib++){
        const int b = bh*16 + ib;
        const int tok = a.trg[b*S_ + t];
        float4 ev = LD4<BF>(a.emb, (size_t)tok*E_ + (lane<<2));
        float ea[4] = {ev.x, ev.y, ev.z, ev.w};
        float s0=0.f, s1=0.f;
        #pragma unroll
        for(int i=0;i<4;i++){ s0 = fmaf(ea[i], wpe[0][i], s0); s1 = fmaf(ea[i], wpe[1][i], s1); }
        const float* cp = &SM[(ib<<10) + (lane<<2)];
        #pragma unroll
        for(int p=0;p<4;p++){
          float4 c4 = *(const float4*)(cp + p*256);
          float ca[4] = {c4.x,c4.y,c4.z,c4.w};
          #pragma unroll
          for(int i=0;i<4;i++){ s0 = fmaf(ca[i], wpc[0][p*4+i], s0); s1 = fmaf(ca[i], wpc[1][p*4+i], s1); }
        }
        s0 = bsum(s0); s1 = bsum(s1);
        if(lane==0){
          stc(&a.xpb[(size_t)t*BDIN_ + (size_t)b*DIN_ + jp],       s0 + pb0);
          stc(&a.xpb[(size_t)t*BDIN_ + (size_t)b*DIN_ + jp + 512], s1 + pb1);
        }
      }
      __syncthreads();
    }
    // ---- cells: gate-split, weights prefetched before each barrier ----
    dec_loadW<BF,4>(a, 0, jp, lane, half, wx, wh, pg);
    gbar(a.flags, ++g);
    dec_cellG<BF,4>(a, SM, t, 0, jp, bh, bh_blk, lane, tid, half, pairid, wx, wh, pg, cvs[0]);
    dec_loadW<BF,2>(a, 1, jp, lane, half, wx, wh, pg);
    gbar(a.flags, ++g);
    dec_cellG<BF,2>(a, SM, t, 1, jp, bh, bh_blk, lane, tid, half, pairid, wx, wh, pg, cvs[1]);
    dec_loadW<BF,2>(a, 2, jp, lane, half, wx, wh, pg);
    gbar(a.flags, ++g);
    dec_cellG<BF,2>(a, SM, t, 2, jp, bh, bh_blk, lane, tid, half, pairid, wx, wh, pg, cvs[2]);
    gbar(a.flags, ++g);
  }
}
__global__ __launch_bounds__(512,1) void k_dec2(DecArgs2 a){
  if(*a.fl) dec2_body<1>(a); else dec2_body<0>(a);
}

// ===========================================================================
// PLAN B fallback (small workspace): round-4 proven kernels, verbatim.
// ===========================================================================
struct EncArgsO {
  const float* G;
  const float* Xin;
  const void* Wih; size_t oWi;
  const void* Whh; size_t oWh;
  const void* bih; size_t obi;
  const void* bhh; size_t obh;
  float* hst; float* cT; float* Xout; float* dh; float* dcT;
  int l; const int* fl; int* flags; int gbase;
};

template<int BF, int CP>
__device__ void encO_body(const EncArgsO& a){
  __shared__ float SM[16384];
  const int tid  = threadIdx.x;
  const int w    = (blockIdx.x<<2) + (tid>>6);
  const int lane = tid & 63;
  const int d    = w >> 9;
  const int j    = w & 511;
  int g = a.gbase;

  float wh[4][8];
  #pragma unroll
  for(int gg=0; gg<4; gg++){
    size_t rowh = a.oWh + ((size_t)d*G4_ + (size_t)gg*H_ + j)*H_;
    #pragma unroll
    for(int p=0;p<2;p++){
      float4 v = LD4<BF>(a.Whh, rowh + (lane<<2) + p*256);
      wh[gg][p*4+0]=v.x; wh[gg][p*4+1]=v.y; wh[gg][p*4+2]=v.z; wh[gg][p*4+3]=v.w;
    }
  }
  float wxf[4][CP?CP*4:1];
  float pbias[4];
  if constexpr(CP>0){
    #pragma unroll
    for(int gg=0; gg<4; gg++){
      size_t rowx = a.oWi + ((size_t)d*G4_ + (size_t)gg*H_ + j)*DIN_;
      #pragma unroll
      for(int p=0;p<CP;p++){
        float4 v = LD4<BF>(a.Wih, rowx + (lane<<2) + p*256);
        wxf[gg][p*4+0]=v.x; wxf[gg][p*4+1]=v.y; wxf[gg][p*4+2]=v.z; wxf[gg][p*4+3]=v.w;
      }
    }
    size_t bb = (size_t)d*G4_ + j;
    #pragma unroll
    for(int gg=0;gg<4;gg++)
      pbias[gg] = LD<BF>(a.bih, a.obi + bb + (size_t)gg*H_)
                + LD<BF>(a.bhh, a.obh + bb + (size_t)gg*H_);
  }
  const int bE = lane & 31;
  const size_t ci = ((size_t)d*H_ + j)*32 + bE;
  float cv = 0.f;
  int cur = 0;
  for(int p=0;p<64;p++){
    const int t = d ? (63-p) : p;
    if(p == 0){
      for(int i=tid<<2; i<BH_; i+=1024) *(float4*)&SM[i] = make_float4(0.f,0.f,0.f,0.f);
    } else {
      const float* hsrc = a.hst + (size_t)((cur<<1)+d)*BH_;
      #pragma unroll 4
      for(int i=tid; i<BH_; i+=256) SM[i] = ldc(hsrc + i);
    }
    __syncthreads();
    float pg[4];
    if constexpr(CP==0){
      const float* Gp = a.G + (size_t)(t*B_+bE)*4096 + (size_t)d*G4_ + j;
      pg[0]=Gp[0]; pg[1]=Gp[512]; pg[2]=Gp[1024]; pg[3]=Gp[1536];
    } else {
      pg[0]=pbias[0]; pg[1]=pbias[1]; pg[2]=pbias[2]; pg[3]=pbias[3];
    }
    const float* xrow = nullptr;
    if constexpr(CP>0) xrow = a.Xin + (size_t)t*B_*DIN_;
    float gv0=0.f, gv1=0.f, gv2=0.f, gv3=0.f;
    for(int b=0;b<32;b++){
      float gs[4] = {0.f,0.f,0.f,0.f};
      const float* hp = &SM[(b<<9) + (lane<<2)];
      #pragma unroll
      for(int pp=0;pp<2;pp++){
        float4 hv = *(const float4*)(hp + pp*256);
        float ha[4] = {hv.x,hv.y,hv.z,hv.w};
        #pragma unroll
        for(int gg=0;gg<4;gg++){
          #pragma unroll
          for(int i=0;i<4;i++) gs[gg] = fmaf(ha[i], wh[gg][pp*4+i], gs[gg]);
        }
      }
      if constexpr(CP>0){
        const float* xr = xrow + (size_t)b*DIN_ + (lane<<2);
        #pragma unroll
        for(int pp=0;pp<CP;pp++){
          float4 xv = *(const float4*)(xr + pp*256);
          float xa[4] = {xv.x,xv.y,xv.z,xv.w};
          #pragma unroll
          for(int gg=0;gg<4;gg++){
            #pragma unroll
            for(int i=0;i<4;i++) gs[gg] = fmaf(xa[i], wxf[gg][pp*4+i], gs[gg]);
          }
        }
      }
      #pragma unroll
      for(int gg=0;gg<4;gg++) gs[gg] = bsum(gs[gg]);
      if(lane == b){ gv0=gs[0]; gv1=gs[1]; gv2=gs[2]; gv3=gs[3]; }
    }
    if(lane < 32){
      float gi = gv0+pg[0], gf = gv1+pg[1], gG = gv2+pg[2], go = gv3+pg[3];
      float c2 = sigm(gf)*cv + sigm(gi)*tanhf(gG);
      float h2 = sigm(go)*tanhf(c2);
      cv = c2;
      stc(&a.hst[(size_t)(((cur^1)<<1)+d)*BH_ + (size_t)bE*H_ + j], h2);
      a.Xout[(size_t)(t*B_+bE)*DIN_ + (d<<9) + j] = h2;
    }
    gbar(a.flags, ++g);
    cur ^= 1;
  }
  if(lane < 32) stc(&a.cT[ci], cv);
  gbar(a.flags, ++g);
  for(int i = blockIdx.x*256 + tid; i < BH_; i += 65536){
    a.dh[(size_t)a.l*BH_ + i]  = ldc(&a.hst[(size_t)(cur<<1)*BH_ + i])
                               + ldc(&a.hst[(size_t)((cur<<1)+1)*BH_ + i]);
    a.dcT[(size_t)a.l*BH_ + i] = ldc(&a.cT[i]) + ldc(&a.cT[BH_ + i]);
  }
}
__global__ __launch_bounds__(256,2) void k_enc_persF0(EncArgsO a){
  if(*a.fl) encO_body<1,1>(a); else encO_body<0,1>(a);
}
__global__ __launch_bounds__(256,2) void k_enc_persF12(EncArgsO a){
  if(*a.fl) encO_body<1,4>(a); else encO_body<0,4>(a);
}

struct DecArgsO {
  const int* trg;
  const void* emb; const void* aW; const void* av; const void* pW; const void* pb;
  const void* dWih; const void* dWhh; const void* dbih; const void* dbhh;
  const void* fW; const void* fb;
  const float* Epre; const float* X3;
  float* dh; float* dcT; float* z; float* ctx; float* xp;
  void* out; const int* fl; int* flags; int gbase;
};

template<int BF, int CP>
__device__ __forceinline__ void decO_cell(const DecArgsO& a, float* SM,
    const int l, const int cur, const int jp, const int bh, const int bh_blk,
    const int lane, const int tid, int& g, float& cv){
  constexpr int Kx = CP*256;
  constexpr int HB = (CP==4) ? 2 : 1;
  constexpr int NB = 16/HB;
  const float* xsrc = (l==0) ? (a.xp + (size_t)bh_blk*16*DIN_)
                             : (a.dh + ((size_t)(cur^1)*3 + (l-1))*BH_ + (size_t)bh_blk*16*H_);
  const float* hsrc = a.dh + ((size_t)cur*3 + l)*BH_ + (size_t)bh_blk*16*H_;
  float wx[4][CP*4];
  float wh[4][8];
  #pragma unroll
  for(int gg=0; gg<4; gg++){
    size_t rowx = ((size_t)l*G4_ + (size_t)gg*H_ + jp)*DIN_;
    #pragma unroll
    for(int p=0;p<CP;p++){
      float4 v = LD4<BF>(a.dWih, rowx + (lane<<2) + p*256);
      wx[gg][p*4+0]=v.x; wx[gg][p*4+1]=v.y; wx[gg][p*4+2]=v.z; wx[gg][p*4+3]=v.w;
    }
    size_t rowh = ((size_t)l*G4_ + (size_t)gg*H_ + jp)*H_;
    #pragma unroll
    for(int p=0;p<2;p++){
      float4 v = LD4<BF>(a.dWhh, rowh + (lane<<2) + p*256);
      wh[gg][p*4+0]=v.x; wh[gg][p*4+1]=v.y; wh[gg][p*4+2]=v.z; wh[gg][p*4+3]=v.w;
    }
  }
  float pg[4];
  {
    size_t bb = (size_t)l*G4_ + jp;
    #pragma unroll
    for(int gg=0;gg<4;gg++)
      pg[gg] = LD<BF>(a.dbih, bb + (size_t)gg*H_) + LD<BF>(a.dbhh, bb + (size_t)gg*H_);
  }
  float gv0=0.f,gv1=0.f,gv2=0.f,gv3=0.f;
  #pragma unroll
  for(int hf=0; hf<HB; hf++){
    const float* xg = xsrc + (size_t)hf*NB*Kx;
    const float* hg = hsrc + (size_t)hf*NB*H_;
    #pragma unroll 4
    for(int i=tid; i<NB*Kx; i+=256) SM[i] = ldc(xg + i);
    #pragma unroll 4
    for(int i=tid; i<NB*H_; i+=256) SM[NB*Kx + i] = ldc(hg + i);
    __syncthreads();
    for(int ib2=0; ib2<NB; ib2++){
      const int ib = hf*NB + ib2;
      float gs[4] = {0.f,0.f,0.f,0.f};
      const float* xr = &SM[ib2*Kx + (lane<<2)];
      #pragma unroll
      for(int p=0;p<CP;p++){
        float4 xv = *(const float4*)(xr + p*256);
        float xa[4] = {xv.x,xv.y,xv.z,xv.w};
        #pragma unroll
        for(int gg=0;gg<4;gg++){
          #pragma unroll
          for(int i=0;i<4;i++) gs[gg] = fmaf(xa[i], wx[gg][p*4+i], gs[gg]);
        }
      }
      const float* hr = &SM[NB*Kx + ib2*H_ + (lane<<2)];
      #pragma unroll
      for(int p=0;p<2;p++){
        float4 hv = *(const float4*)(hr + p*256);
        float ha[4] = {hv.x,hv.y,hv.z,hv.w};
        #pragma unroll
        for(int gg=0;gg<4;gg++){
          #pragma unroll
          for(int i=0;i<4;i++) gs[gg] = fmaf(ha[i], wh[gg][p*4+i], gs[gg]);
        }
      }
      #pragma unroll
      for(int gg=0;gg<4;gg++) gs[gg] = bsum(gs[gg]);
      if(lane == ib){ gv0=gs[0]; gv1=gs[1]; gv2=gs[2]; gv3=gs[3]; }
    }
    __syncthreads();
  }
  if(lane < 16){
    const int b = bh*16 + lane;
    float gi = gv0+pg[0], gf = gv1+pg[1], gG = gv2+pg[2], go = gv3+pg[3];
    float c2 = sigm(gf)*cv + sigm(gi)*tanhf(gG);
    float h2 = sigm(go)*tanhf(c2);
    cv = c2;
    stc(&a.dh[((size_t)(cur^1)*3 + l)*BH_ + (size_t)b*H_ + jp], h2);
  }
  gbar(a.flags, ++g);
}

template<int BF>
__device__ void decO_body(const DecArgsO& a){
  __shared__ float SM[16384];
  const int tid  = threadIdx.x;
  const int w    = (blockIdx.x<<2) + (tid>>6);
  const int lane = tid & 63;
  const int jp   = w & 511;
  const int bh   = w >> 9;
  const int bh_blk = blockIdx.x >> 7;
  int g = a.gbase;
  float cvs[3];
  #pragma unroll
  for(int l=0;l<3;l++)
    cvs[l] = a.dcT[((size_t)l*H_ + jp)*32 + (size_t)bh*16 + (lane&15)];
  int cur = 0;
  for(int t=0; t<64; ++t){
    {
      const float* hs = a.dh + ((size_t)cur*3 + 2)*BH_ + (size_t)bh_blk*16*H_;
      #pragma unroll 4
      for(int i=tid; i<16*H_; i+=256) SM[i] = ldc(hs + i);
      __syncthreads();
      if(t < 63){
        float wz[8];
        size_t rz = (size_t)jp*1536;
        #pragma unroll
        for(int p=0;p<2;p++){
          float4 v = LD4<BF>(a.aW, rz + (lane<<2) + p*256);
          wz[p*4+0]=v.x; wz[p*4+1]=v.y; wz[p*4+2]=v.z; wz[p*4+3]=v.w;
        }
        for(int ib=0; ib<16; ib++){
          const float* hp = &SM[(ib<<9) + (lane<<2)];
          float acc = 0.f;
          #pragma unroll
          for(int p=0;p<2;p++){
            float4 hv = *(const float4*)(hp + p*256);
            acc = fmaf(hv.x, wz[p*4+0], acc); acc = fmaf(hv.y, wz[p*4+1], acc);
            acc = fmaf(hv.z, wz[p*4+2], acc); acc = fmaf(hv.w, wz[p*4+3], acc);
          }
          acc = bsum(acc);
          if(lane==0) stc(&a.z[(size_t)(bh*16+ib)*H_ + jp], acc);
        }
      }
      if(t > 0){
        #pragma unroll
        for(int r=0;r<3;r++){
          const int q  = jp + (r<<9);
          const int v_ = q % 96;
          const int ib = q / 96;
          float wf[8];
          size_t rf = (size_t)v_*H_;
          #pragma unroll
          for(int p=0;p<2;p++){
            float4 v = LD4<BF>(a.fW, rf + (lane<<2) + p*256);
            wf[p*4+0]=v.x; wf[p*4+1]=v.y; wf[p*4+2]=v.z; wf[p*4+3]=v.w;
          }
          const float* hp = &SM[(ib<<9) + (lane<<2)];
          float acc = 0.f;
          #pragma unroll
          for(int p=0;p<2;p++){
            float4 hv = *(const float4*)(hp + p*256);
            acc = fmaf(hv.x, wf[p*4+0], acc); acc = fmaf(hv.y, wf[p*4+1], acc);
            acc = fmaf(hv.z, wf[p*4+2], acc); acc = fmaf(hv.w, wf[p*4+3], acc);
          }
          acc = bsum(acc);
          if(lane==0){
            float rr = acc + LD<BF>(a.fb, v_);
            size_t oi = (size_t)(bh*16+ib)*(S_*V_) + (size_t)t*V_ + v_;
            if constexpr(BF) ((u16*)a.out)[oi] = f2b(rr);
            else             ((float*)a.out)[oi] = rr;
          }
        }
      }
    }
    if(t == 63) break;
    gbar(a.flags, ++g);
    if(blockIdx.x < 32){
      const int b = blockIdx.x;
      float* Zs = SM; float* Ss = SM + 512;
      for(int i=tid; i<512; i+=256) Zs[i] = ldc(a.z + (size_t)b*H_ + i);
      __syncthreads();
      float wa[8];
      #pragma unroll
      for(int p=0;p<2;p++){
        float4 v = LD4<BF>(a.av, (lane<<2) + p*256);
        wa[p*4+0]=v.x; wa[p*4+1]=v.y; wa[p*4+2]=v.z; wa[p*4+3]=v.w;
      }
      const int ww = tid>>6;
      for(int s=ww; s<64; s+=4){
        const float* ep = a.Epre + ((size_t)(s*B_ + b))*H_;
        float acc = 0.f;
        #pragma unroll
        for(int p=0;p<2;p++){
          const float4 e4 = *(const float4*)(ep + (lane<<2) + p*256);
          const float4 z4 = *(const float4*)(Zs + (lane<<2) + p*256);
          acc = fmaf(wa[p*4+0], tanhf(e4.x+z4.x), acc);
          acc = fmaf(wa[p*4+1], tanhf(e4.y+z4.y), acc);
          acc = fmaf(wa[p*4+2], tanhf(e4.z+z4.z), acc);
          acc = fmaf(wa[p*4+3], tanhf(e4.w+z4.w), acc);
        }
        acc = bsum(acc);
        if(lane==0) Ss[s] = acc;
      }
      __syncthreads();
      if(tid < 64){
        float vv = Ss[tid];
        float m = vv;
        #pragma unroll
        for(int off=1; off<64; off<<=1) m = fmaxf(m, __shfl_xor(m, off));
        float e = __expf(vv - m);
        float su = e;
        #pragma unroll
        for(int off=1; off<64; off<<=1) su += __shfl_xor(su, off);
        Ss[tid] = e / su;
      }
      __syncthreads();
      for(int d4 = tid<<2; d4 < DIN_; d4 += 1024){
        float a0=0.f,a1=0.f,a2=0.f,a3=0.f;
        const float* xb = a.X3 + (size_t)b*DIN_ + d4;
        for(int s=0;s<64;s++){
          const float pp = Ss[s];
          const float4 xv = *(const float4*)(xb + (size_t)s*BDIN_);
          a0 = fmaf(pp, xv.x, a0); a1 = fmaf(pp, xv.y, a1);
          a2 = fmaf(pp, xv.z, a2); a3 = fmaf(pp, xv.w, a3);
        }
        float* cp = &a.ctx[(size_t)b*DIN_ + d4];
        stc(cp+0, a0); stc(cp+1, a1); stc(cp+2, a2); stc(cp+3, a3);
      }
    }
    gbar(a.flags, ++g);
    {
      const float* cs = a.ctx + (size_t)bh_blk*16*DIN_;
      #pragma unroll 4
      for(int i=tid; i<16*DIN_; i+=256) SM[i] = ldc(cs + i);
      __syncthreads();
      float wpe[2][4], wpc[2][16];
      #pragma unroll
      for(int jj=0;jj<2;jj++){
        size_t row = (size_t)(jp + (jj<<9))*1280;
        float4 v = LD4<BF>(a.pW, row + (lane<<2));
        wpe[jj][0]=v.x; wpe[jj][1]=v.y; wpe[jj][2]=v.z; wpe[jj][3]=v.w;
        #pragma unroll
        for(int p=0;p<4;p++){
          float4 c4 = LD4<BF>(a.pW, row + 256 + (lane<<2) + p*256);
          wpc[jj][p*4+0]=c4.x; wpc[jj][p*4+1]=c4.y; wpc[jj][p*4+2]=c4.z; wpc[jj][p*4+3]=c4.w;
        }
      }
      const float pb0 = LD<BF>(a.pb, jp);
      const float pb1 = LD<BF>(a.pb, jp+512);
      for(int ib=0; ib<16; ib++){
        const int b = bh*16 + ib;
        const int tok = a.trg[b*S_ + t];
        float4 ev = LD4<BF>(a.emb, (size_t)tok*E_ + (lane<<2));
        float ea[4] = {ev.x, ev.y, ev.z, ev.w};
        float s0=0.f, s1=0.f;
        #pragma unroll
        for(int i=0;i<4;i++){ s0 = fmaf(ea[i], wpe[0][i], s0); s1 = fmaf(ea[i], wpe[1][i], s1); }
        const float* cp = &SM[(ib<<10) + (lane<<2)];
        #pragma unroll
        for(int p=0;p<4;p++){
          float4 c4 = *(const float4*)(cp + p*256);
          float ca[4] = {c4.x,c4.y,c4.z,c4.w};
          #pragma unroll
          for(int i=0;i<4;i++){ s0 = fmaf(ca[i], wpc[0][p*4+i], s0); s1 = fmaf(ca[i], wpc[1][p*4+i], s1); }
        }
        s0 = bsum(s0); s1 = bsum(s1);
        if(lane==0){
          stc(&a.xp[(size_t)b*DIN_ + jp],       s0 + pb0);
          stc(&a.xp[(size_t)b*DIN_ + jp + 512], s1 + pb1);
        }
      }
    }
    gbar(a.flags, ++g);
    decO_cell<BF,4>(a, SM, 0, cur, jp, bh, bh_blk, lane, tid, g, cvs[0]);
    decO_cell<BF,2>(a, SM, 1, cur, jp, bh, bh_blk, lane, tid, g, cvs[1]);
    decO_cell<BF,2>(a, SM, 2, cur, jp, bh, bh_blk, lane, tid, g, cvs[2]);
    cur ^= 1;
  }
}
__global__ __launch_bounds__(256,2) void k_dec_persO(DecArgsO a){
  if(*a.fl) decO_body<1>(a); else decO_body<0>(a);
}

// ---------------------------------------------------------------------------
extern "C" void kernel_launch(void* const* d_in, const int* in_sizes, int n_in,
                              void* d_out, int out_size, void* d_ws, size_t ws_size,
                              hipStream_t stream){
  const int* src  = (const int*)d_in[0];
  const int* trg  = (const int*)d_in[1];
  const void* emb = d_in[2];
  const void* eWih= d_in[3];
  const void* eWhh= d_in[4];
  const void* ebih= d_in[5];
  const void* ebhh= d_in[6];
  const void* dWih= d_in[7];
  const void* dWhh= d_in[8];
  const void* dbih= d_in[9];
  const void* dbhh= d_in[10];
  const void* aW  = d_in[11];
  const void* ab  = d_in[12];
  const void* av  = d_in[13];
  const void* pW  = d_in[14];
  const void* pb  = d_in[15];
  const void* fW  = d_in[16];
  const void* fb  = d_in[17];

  char* base = (char*)d_ws;
  size_t off = 0;
  auto take = [&](size_t bytes)->char*{
    char* p = base + off; off = (off + bytes + 255) & ~(size_t)255; return p;
  };

  const size_t szX  = (size_t)2048*1024*4;   // 8 MB
  const size_t szG  = (size_t)2048*4096*4;   // 32 MB
  const size_t szE  = (size_t)2048*512*4;    // 4 MB
  int planA = ws_size >= (size_t)53*1024*1024;

  if(planA){
    float* X    = (float*)take(szX);               // Xin/Xout in-place
    float* Xh   = (float*)take(szX);               // henc: 64 slots * 2 * BH * 4 = 8 MB
    float* G    = (float*)take(szG);
    // decoder t-indexed buffers overlay G (dead after encoder):
    float* dhb  = G;                               // 64*3*BH f
    float* zb   = dhb + (size_t)64*3*BH_;          // 63*BH f
    float* xpb  = zb  + (size_t)63*BH_;            // 63*B*DIN f
    u16*   ctxb = (u16*)(xpb + (size_t)63*BDIN_);  // 63*B*DIN u16   total 29.1 MB <= 32
    float* Epre = (float*)take(szE);
    float* cTe  = (float*)take((size_t)2*BH_*4);
    float* dh0  = (float*)take((size_t)3*BH_*4);
    float* dcT  = (float*)take((size_t)3*BH_*4);
    int* fl     = (int*)take(256);
    int* flags  = (int*)take((256*FSTRIDE + 16)*4);

    k_detect<<<1, 256, 0, stream>>>(av, fl, flags);
    k_embed<<<8192, 256, 0, stream>>>(src, emb, X, fl);

    for(int l=0;l<L_;l++){
      int K = (l==0) ? E_ : DIN_;
      k_gemm<<<dim3(64,16), 256, 0, stream>>>(X, DIN_,
          eWih, DIN_, (size_t)l*2*G4_*DIN_,
          ebih, (size_t)l*2*G4_, ebhh, (size_t)l*2*G4_,
          G, 4096, K, fl);
      EncArgs2 ea;
      ea.G = G; ea.Whh = eWhh; ea.oWh = (size_t)l*2*G4_*H_;
      ea.henc = Xh; ea.cT = cTe; ea.Xout = X;
      ea.dh0 = dh0; ea.dcT = dcT; ea.l = l;
      ea.fl = fl; ea.flags = flags; ea.gbase = l*65;
      k_enc2<<<256, 512, 0, stream>>>(ea);
    }
    k_gemm<<<dim3(8,16), 256, 0, stream>>>(X, DIN_,
        aW, 3*H_, (size_t)H_, ab, 0, nullptr, 0, Epre, H_, DIN_, fl);
    k_outzero<<<12, 256, 0, stream>>>(d_out, fl);

    DecArgs2 da;
    da.trg = trg; da.emb = emb; da.aW = aW; da.av = av; da.pW = pW; da.pb = pb;
    da.dWih = dWih; da.dWhh = dWhh; da.dbih = dbih; da.dbhh = dbhh;
    da.fW = fW; da.fb = fb;
    da.Epre = Epre; da.X3 = X;
    da.dh0 = dh0; da.dhb = dhb; da.zb = zb; da.ctxb = ctxb; da.xpb = xpb;
    da.dcT = dcT; da.out = d_out; da.fl = fl; da.flags = flags; da.gbase = 3*65;
    k_dec2<<<256, 512, 0, stream>>>(da);
  } else {
    // -------- fallback: round-4 proven path (fused encoder + ldc decoder) --------
    float* XA   = (float*)take(szX);
    float* XB   = (float*)take(szX);
    float* Epre = (float*)take(szE);
    float* hst  = (float*)take((size_t)4*BH_*4);
    float* cTe  = (float*)take((size_t)2*BH_*4);
    float* dh   = (float*)take((size_t)6*BH_*4);
    float* dcT  = (float*)take((size_t)3*BH_*4);
    float* zbuf = (float*)take((size_t)BH_*4);
    float* ctx  = (float*)take((size_t)2*BH_*4);
    float* xp   = (float*)take((size_t)2*BH_*4);
    int* fl     = (int*)take(256);
    int* flags  = (int*)take((256*FSTRIDE + 16)*4);

    k_detect<<<1, 256, 0, stream>>>(av, fl, flags);
    k_embed<<<8192, 256, 0, stream>>>(src, emb, XA, fl);

    float* Xin = XA; float* Xout = XB;
    for(int l=0;l<L_;l++){
      EncArgsO ea;
      ea.G = nullptr; ea.Xin = Xin;
      ea.Wih = eWih; ea.oWi = (size_t)l*2*G4_*DIN_;
      ea.Whh = eWhh; ea.oWh = (size_t)l*2*G4_*H_;
      ea.bih = ebih; ea.obi = (size_t)l*2*G4_;
      ea.bhh = ebhh; ea.obh = (size_t)l*2*G4_;
      ea.hst = hst; ea.cT = cTe; ea.Xout = Xout;
      ea.dh = dh; ea.dcT = dcT; ea.l = l;
      ea.fl = fl; ea.flags = flags; ea.gbase = l*65;
      if(l == 0) k_enc_persF0<<<256, 256, 0, stream>>>(ea);
      else       k_enc_persF12<<<256, 256, 0, stream>>>(ea);
      float* tmp = Xin; Xin = Xout; Xout = tmp;
    }
    k_gemm<<<dim3(8,16), 256, 0, stream>>>(Xin, DIN_,
        aW, 3*H_, (size_t)H_, ab, 0, nullptr, 0, Epre, H_, DIN_, fl);
    k_outzero<<<12, 256, 0, stream>>>(d_out, fl);

    DecArgsO da;
    da.trg = trg; da.emb = emb; da.aW = aW; da.av = av; da.pW = pW; da.pb = pb;
    da.dWih = dWih; da.dWhh = dWhh; da.dbih = dbih; da.dbhh = dbhh;
    da.fW = fW; da.fb = fb;
    da.Epre = Epre; da.X3 = Xin;
    da.dh = dh; da.dcT = dcT; da.z = zbuf; da.ctx = ctx; da.xp = xp;
    da.out = d_out; da.fl = fl; da.flags = flags; da.gbase = 3*65;
    k_dec_persO<<<256, 256, 0, stream>>>(da);
  }
}

// Round 11
// 9570.455 us; speedup vs baseline: 2.1369x; 1.0014x over previous
//
#include <hip/hip_runtime.h>

#define B_ 32
#define S_ 64
#define V_ 96
#define E_ 256
#define H_ 512
#define L_ 3
#define DIN_ 1024
#define G4_ 2048
#define BH_ (B_*H_)
#define BDIN_ (B_*DIN_)
#define FSTRIDE 16   // flags spaced 64B apart

typedef unsigned short u16;

__device__ __forceinline__ float bfu(u16 u){ return __uint_as_float(((unsigned)u) << 16); }
__device__ __forceinline__ u16 f2b(float f){           // RNE float->bf16
  unsigned x = __float_as_uint(f);
  unsigned r = (x + 0x7FFFu + ((x >> 16) & 1u)) >> 16;
  return (u16)r;
}
__device__ __forceinline__ float sigm(float x){ return 1.f/(1.f+__expf(-x)); }
__device__ __forceinline__ float bsum(float a){
  #pragma unroll
  for(int off=1; off<64; off<<=1) a += __shfl_xor(a, off);
  return a;
}
// Coherent (LLC-point) access: relaxed agent-scope atomics emit sc0/sc1
// load/store -- per-access coherence, NO cache wb/inv instructions.
__device__ __forceinline__ void stc(float* p, float v){
  __hip_atomic_store(p, v, __ATOMIC_RELAXED, __HIP_MEMORY_SCOPE_AGENT);
}
__device__ __forceinline__ float ldc(const float* p){
  return __hip_atomic_load((float*)p, __ATOMIC_RELAXED, __HIP_MEMORY_SCOPE_AGENT);
}
__device__ __forceinline__ void stci(int* p, int v){
  __hip_atomic_store(p, v, __ATOMIC_RELAXED, __HIP_MEMORY_SCOPE_AGENT);
}
__device__ __forceinline__ int ldci(const int* p){
  return __hip_atomic_load((int*)p, __ATOMIC_RELAXED, __HIP_MEMORY_SCOPE_AGENT);
}
// Dual-dtype INPUT loads. BF=1: buffer is bf16 (u16); BF=0: buffer is fp32.
template<int BF> __device__ __forceinline__ float LD(const void* p, size_t i){
  if constexpr(BF) return bfu(((const u16*)p)[i]);
  else             return ((const float*)p)[i];
}
template<int BF> __device__ __forceinline__ float4 LD4(const void* p, size_t i){
  if constexpr(BF){
    const u16* q = (const u16*)p + i;
    ushort4 w = *(const ushort4*)q;
    return make_float4(bfu(w.x), bfu(w.y), bfu(w.z), bfu(w.w));
  } else {
    return *(const float4*)((const float*)p + i);
  }
}

// ---------------------------------------------------------------------------
// Distributed contention-free grid barrier (round-4 proven).
__device__ __forceinline__ void gbar(int* flags, int g){
  __syncthreads();
  if(threadIdx.x < 64){
    if(threadIdx.x == 0) stci(&flags[blockIdx.x*FSTRIDE], g);
    const int i0 = threadIdx.x*4;
    for(;;){
      int f0 = ldci(&flags[(i0+0)*FSTRIDE]);
      int f1 = ldci(&flags[(i0+1)*FSTRIDE]);
      int f2 = ldci(&flags[(i0+2)*FSTRIDE]);
      int f3 = ldci(&flags[(i0+3)*FSTRIDE]);
      bool ok = (f0>=g) && (f1>=g) && (f2>=g) && (f3>=g);
      if(__all(ok)) break;
      __builtin_amdgcn_s_sleep(1);
    }
  }
  __syncthreads();
}

// ---------------------------------------------------------------------------
__global__ void k_detect(const void* av, int* flag, int* flags){
  __shared__ int cnt;
  if(threadIdx.x == 0) cnt = 0;
  __syncthreads();
  u16 w = ((const u16*)av)[2*threadIdx.x];
  if(w & 0x8000) atomicAdd(&cnt, 1);
  __syncthreads();
  for(int i=threadIdx.x; i<256*FSTRIDE+16; i+=256) flags[i] = 0;
  if(threadIdx.x == 0) *flag = (cnt <= 8) ? 1 : 0;   // 1 = bf16 inputs
}

// ---------------------------------------------------------------------------
template<int BF> __device__ void embed_body(const int* __restrict__ src,
                                            const void* __restrict__ emb,
                                            float* __restrict__ X0){
  int idx = blockIdx.x*256 + threadIdx.x;   // exactly S*B*DIN threads
  int d  = idx & (DIN_-1);
  int sb = idx >> 10;
  int b  = sb & (B_-1);
  int s  = sb >> 5;
  float v = 0.f;
  if(d < E_){
    int tok = src[b*S_ + s];
    v = LD<BF>(emb, (size_t)tok*E_ + d);
  }
  X0[idx] = v;
}
__global__ void k_embed(const int* src, const void* emb, float* X0, const int* fl){
  if(*fl) embed_body<1>(src, emb, X0); else embed_body<0>(src, emb, X0);
}

// ---------------------------------------------------------------------------
// Tiled GEMM: C[m,n] = sum_k A[m*lda+k] * W[woff + n*ldw + k] + b1[n] + b2[n]
template<int BF> __device__ void gemm_body(
  const float* __restrict__ A, int lda,
  const void* __restrict__ W, int ldw, size_t woff,
  const void* __restrict__ b1, size_t o1,
  const void* __restrict__ b2, size_t o2,
  float* __restrict__ C, int ldc, int K)
{
  __shared__ float As[16][128];
  __shared__ float Bs[16][64];
  const int tid = threadIdx.x;
  const int m0 = blockIdx.y * 128;
  const int n0 = blockIdx.x * 64;
  const int tx = tid & 15, ty = tid >> 4;
  const int amm = tid & 127, akk = (tid >> 7) * 8;
  const int bnn = tid >> 2,  bkk = (tid & 3) * 4;
  float acc[8][4] = {{0.f}};
  for(int k0 = 0; k0 < K; k0 += 16){
    const float4* ap = (const float4*)(A + (size_t)(m0+amm)*lda + (k0 + akk));
    float4 a0 = ap[0];
    float4 a1 = ap[1];
    float4 wv = LD4<BF>(W, woff + (size_t)(n0+bnn)*ldw + (k0 + bkk));
    As[akk+0][amm]=a0.x; As[akk+1][amm]=a0.y; As[akk+2][amm]=a0.z; As[akk+3][amm]=a0.w;
    As[akk+4][amm]=a1.x; As[akk+5][amm]=a1.y; As[akk+6][amm]=a1.z; As[akk+7][amm]=a1.w;
    Bs[bkk+0][bnn]=wv.x; Bs[bkk+1][bnn]=wv.y;
    Bs[bkk+2][bnn]=wv.z; Bs[bkk+3][bnn]=wv.w;
    __syncthreads();
    #pragma unroll
    for(int kk=0;kk<16;kk++){
      const float4 av0 = *(const float4*)&As[kk][ty*8];
      const float4 av1 = *(const float4*)&As[kk][ty*8+4];
      const float4 bv  = *(const float4*)&Bs[kk][tx*4];
      float am[8] = {av0.x,av0.y,av0.z,av0.w,av1.x,av1.y,av1.z,av1.w};
      float bn[4] = {bv.x,bv.y,bv.z,bv.w};
      #pragma unroll
      for(int i=0;i<8;i++){
        #pragma unroll
        for(int j=0;j<4;j++) acc[i][j] = fmaf(am[i], bn[j], acc[i][j]);
      }
    }
    __syncthreads();
  }
  float bias[4];
  #pragma unroll
  for(int j=0;j<4;j++){
    float bb = 0.f;
    if(b1) bb += LD<BF>(b1, o1 + n0 + tx*4 + j);
    if(b2) bb += LD<BF>(b2, o2 + n0 + tx*4 + j);
    bias[j] = bb;
  }
  #pragma unroll
  for(int i=0;i<8;i++){
    float* cp = C + (size_t)(m0 + ty*8 + i)*ldc + (n0 + tx*4);
    #pragma unroll
    for(int j=0;j<4;j++) cp[j] = acc[i][j] + bias[j];
  }
}
__global__ __launch_bounds__(256) void k_gemm(
  const float* A, int lda, const void* W, int ldw, size_t woff,
  const void* b1, size_t o1, const void* b2, size_t o2,
  float* C, int ldc, int K, const int* fl)
{
  if(*fl) gemm_body<1>(A,lda,W,ldw,woff,b1,o1,b2,o2,C,ldc,K);
  else    gemm_body<0>(A,lda,W,ldw,woff,b1,o1,b2,o2,C,ldc,K);
}

// ---------------------------------------------------------------------------
__global__ void k_outzero(void* __restrict__ out, const int* fl){
  int i = blockIdx.x*256 + threadIdx.x;
  if(i < B_*V_){
    int b = i / V_, v = i % V_;
    size_t idx = (size_t)b*(S_*V_) + v;
    if(*fl) ((u16*)out)[idx] = 0;
    else    ((float*)out)[idx] = 0.f;
  }
}

// ===========================================================================
// ENCODER (round-8 proven, unchanged): 512-thread wave-pair persistent kernel.
// ===========================================================================
struct EncArgs2 {
  const float* G;
  const void* Whh; size_t oWh;
  float* henc;   // [64 gen-slots][2 dir][BH] fp32  (slot = gen & 63)
  float* cT;     // [2 dir][j*32+b] coherent
  float* Xout;   // [(t*B+b)][DIN]
  float* dh0;    // decoder h init [3][BH]
  float* dcT;    // decoder c init [3][j*32+b]
  int l;
  const int* fl;
  int* flags; int gbase;
};

template<int BF>
__device__ void enc2_body(const EncArgs2& a){
  __shared__ float SM[16384];
  const int tid  = threadIdx.x;
  const int lane = tid & 63;
  const int wid  = tid >> 6;                 // 0..7
  const int w4   = (blockIdx.x<<2) + (wid & 3);
  const int j    = w4 & 511;
  const int d    = w4 >> 9;
  const int half = wid >> 2;                 // wave-pair half
  int g = a.gbase;

  float wh[4][8];
  #pragma unroll
  for(int gg=0; gg<4; gg++){
    size_t rowh = a.oWh + ((size_t)d*G4_ + (size_t)gg*H_ + j)*H_;
    #pragma unroll
    for(int p=0;p<2;p++){
      float4 v = LD4<BF>(a.Whh, rowh + (lane<<2) + p*256);
      wh[gg][p*4+0]=v.x; wh[gg][p*4+1]=v.y; wh[gg][p*4+2]=v.z; wh[gg][p*4+3]=v.w;
    }
  }
  const bool own = (lane < 32) && ((lane>>4) == half);   // this wave's batches
  const size_t ci = ((size_t)d*H_ + j)*32 + (lane & 31);
  float cv = 0.f;

  for(int p=0;p<64;p++){
    const int t = d ? (63-p) : p;
    if(p == 0){
      for(int i=tid<<2; i<BH_; i+=2048) *(float4*)&SM[i] = make_float4(0.f,0.f,0.f,0.f);
    } else {
      const float* hsrc = a.henc + (size_t)((p&63)*2 + d)*BH_;  // slot p, fresh
      for(int i=tid<<2; i<BH_; i+=2048) *(float4*)&SM[i] = *(const float4*)&hsrc[i];
    }
    __syncthreads();

    const int bE = lane & 31;
    const float* Gp = a.G + (size_t)(t*B_+bE)*4096 + (size_t)d*G4_ + j;
    float pg0=Gp[0], pg1=Gp[512], pg2=Gp[1024], pg3=Gp[1536];

    float gv0=0.f, gv1=0.f, gv2=0.f, gv3=0.f;
    for(int b=half*16; b<half*16+16; b++){
      float gs[4] = {0.f,0.f,0.f,0.f};
      const float* hp = &SM[(b<<9) + (lane<<2)];
      #pragma unroll
      for(int pp=0;pp<2;pp++){
        float4 hv = *(const float4*)(hp + pp*256);
        float ha[4] = {hv.x,hv.y,hv.z,hv.w};
        #pragma unroll
        for(int gg=0;gg<4;gg++){
          #pragma unroll
          for(int i=0;i<4;i++) gs[gg] = fmaf(ha[i], wh[gg][pp*4+i], gs[gg]);
        }
      }
      #pragma unroll
      for(int gg=0;gg<4;gg++) gs[gg] = bsum(gs[gg]);
      if(lane == b){ gv0=gs[0]; gv1=gs[1]; gv2=gs[2]; gv3=gs[3]; }
    }
    if(own){
      float gi = gv0+pg0, gf = gv1+pg1, gG = gv2+pg2, go = gv3+pg3;
      float c2 = sigm(gf)*cv + sigm(gi)*tanhf(gG);
      float h2 = sigm(go)*tanhf(c2);
      cv = c2;
      stc(&a.henc[(size_t)(((p+1)&63)*2 + d)*BH_ + (size_t)lane*H_ + j], h2);
      a.Xout[(size_t)(t*B_+lane)*DIN_ + (d<<9) + j] = h2;
    }
    gbar(a.flags, ++g);
  }
  if(own) stc(&a.cT[ci], cv);
  gbar(a.flags, ++g);
  for(int i = blockIdx.x*512 + tid; i < BH_; i += 131072){
    float hf2 = a.henc[(size_t)(0*2+0)*BH_ + i];
    float hb2 = a.henc[(size_t)(0*2+1)*BH_ + i];
    a.dh0[(size_t)a.l*BH_ + i] = hf2 + hb2;
    a.dcT[(size_t)a.l*BH_ + i] = ldc(&a.cT[i]) + ldc(&a.cT[BH_ + i]);
  }
}
__global__ __launch_bounds__(512,1) void k_enc2(EncArgs2 a){
  if(*a.fl) enc2_body<1>(a); else enc2_body<0>(a);
}

// ===========================================================================
// DECODER (plan A7): R10 gate-split structure + balanced ATT (all 256 blocks,
// 8 per batch, redundant softmax, 128-dim ctx slice each) + 2-way split
// accumulators in cell/PROJ/ctx dot chains (halves serial FMA latency).
// ===========================================================================
struct DecArgs2 {
  const int* trg;
  const void* emb; const void* aW; const void* av; const void* pW; const void* pb;
  const void* dWih; const void* dWhh; const void* dbih; const void* dbhh;
  const void* fW; const void* fb;
  const float* Epre; const float* X3;
  const float* dh0;   // [3][BH] initial h (from encoder)
  float* dhb;   // [64 t-slots][3][BH] fp32 (slot t = state entering step t)
  float* zb;    // [63][B][H] fp32
  u16*   ctxb;  // [63][B][DIN] bf16
  float* xpb;   // [63][B][DIN] fp32
  const float* dcT;  // [3][j*32+b]
  void* out;
  const int* fl;
  int* flags; int gbase;
};

// Load this wave's 2 gates' weights (gates 2*half, 2*half+1).
template<int BF, int CP>
__device__ __forceinline__ void dec_loadW(const DecArgs2& a, const int l,
    const int jp, const int lane, const int half,
    float wx[2][16], float wh[2][8], float pg[2]){
  #pragma unroll
  for(int gg=0; gg<2; gg++){
    const int gr = half*2 + gg;
    size_t rowx = ((size_t)l*G4_ + (size_t)gr*H_ + jp)*DIN_;
    #pragma unroll
    for(int p=0;p<CP;p++){
      float4 v = LD4<BF>(a.dWih, rowx + (lane<<2) + p*256);
      wx[gg][p*4+0]=v.x; wx[gg][p*4+1]=v.y; wx[gg][p*4+2]=v.z; wx[gg][p*4+3]=v.w;
    }
    size_t rowh = ((size_t)l*G4_ + (size_t)gr*H_ + jp)*H_;
    #pragma unroll
    for(int p=0;p<2;p++){
      float4 v = LD4<BF>(a.dWhh, rowh + (lane<<2) + p*256);
      wh[gg][p*4+0]=v.x; wh[gg][p*4+1]=v.y; wh[gg][p*4+2]=v.z; wh[gg][p*4+3]=v.w;
    }
    size_t bb = (size_t)l*G4_ + (size_t)gr*H_ + jp;
    pg[gg] = LD<BF>(a.dbih, bb) + LD<BF>(a.dbhh, bb);
  }
}

template<int BF, int CP>   // Kx = CP*256
__device__ __forceinline__ void dec_cellG(const DecArgs2& a, float* SM,
    const int t, const int l, const int jp, const int bh, const int bh_blk,
    const int lane, const int tid, const int half, const int pairid,
    float wx[2][16], float wh[2][8], float pg[2], float& cv){
  constexpr int Kx  = CP*256;
  constexpr int HB  = (CP==4) ? 2 : 1;
  constexpr int NBs = 16/HB;       // batches staged per hf
  const float* xsrc = (l==0) ? (a.xpb + (size_t)t*BDIN_ + (size_t)bh_blk*16*DIN_)
                             : (a.dhb + (size_t)((t+1)*3 + (l-1))*BH_ + (size_t)bh_blk*16*H_);
  const float* hsrc = (t==0) ? (a.dh0 + (size_t)l*BH_ + (size_t)bh_blk*16*H_)
                             : (a.dhb + (size_t)(t*3 + l)*BH_ + (size_t)bh_blk*16*H_);
  float gvA=0.f, gvB=0.f;   // this wave's 2 gate partials (lane ib holds batch ib)
  #pragma unroll
  for(int hf=0; hf<HB; hf++){
    const float* xg = xsrc + (size_t)hf*NBs*Kx;
    const float* hg = hsrc + (size_t)hf*NBs*H_;
    for(int i=tid<<2; i<NBs*Kx; i+=2048) *(float4*)&SM[i] = *(const float4*)&xg[i];
    for(int i=tid<<2; i<NBs*H_; i+=2048) *(float4*)&SM[NBs*Kx + i] = *(const float4*)&hg[i];
    __syncthreads();
    for(int ib2=0; ib2<NBs; ib2++){
      const int ib = hf*NBs + ib2;
      float g0a=0.f,g0b=0.f,g1a=0.f,g1b=0.f;   // 2-way split accumulators
      const float* xr = &SM[ib2*Kx + (lane<<2)];
      #pragma unroll
      for(int p=0;p<CP;p++){
        float4 xv = *(const float4*)(xr + p*256);
        if(p & 1){
          g0b = fmaf(xv.x, wx[0][p*4+0], g0b); g0b = fmaf(xv.y, wx[0][p*4+1], g0b);
          g0b = fmaf(xv.z, wx[0][p*4+2], g0b); g0b = fmaf(xv.w, wx[0][p*4+3], g0b);
          g1b = fmaf(xv.x, wx[1][p*4+0], g1b); g1b = fmaf(xv.y, wx[1][p*4+1], g1b);
          g1b = fmaf(xv.z, wx[1][p*4+2], g1b); g1b = fmaf(xv.w, wx[1][p*4+3], g1b);
        } else {
          g0a = fmaf(xv.x, wx[0][p*4+0], g0a); g0a = fmaf(xv.y, wx[0][p*4+1], g0a);
          g0a = fmaf(xv.z, wx[0][p*4+2], g0a); g0a = fmaf(xv.w, wx[0][p*4+3], g0a);
          g1a = fmaf(xv.x, wx[1][p*4+0], g1a); g1a = fmaf(xv.y, wx[1][p*4+1], g1a);
          g1a = fmaf(xv.z, wx[1][p*4+2], g1a); g1a = fmaf(xv.w, wx[1][p*4+3], g1a);
        }
      }
      const float* hr = &SM[NBs*Kx + ib2*H_ + (lane<<2)];
      {
        float4 hv = *(const float4*)(hr);
        g0a = fmaf(hv.x, wh[0][0], g0a); g0a = fmaf(hv.y, wh[0][1], g0a);
        g0a = fmaf(hv.z, wh[0][2], g0a); g0a = fmaf(hv.w, wh[0][3], g0a);
        g1a = fmaf(hv.x, wh[1][0], g1a); g1a = fmaf(hv.y, wh[1][1], g1a);
        g1a = fmaf(hv.z, wh[1][2], g1a); g1a = fmaf(hv.w, wh[1][3], g1a);
      }
      {
        float4 hv = *(const float4*)(hr + 256);
        g0b = fmaf(hv.x, wh[0][4], g0b); g0b = fmaf(hv.y, wh[0][5], g0b);
        g0b = fmaf(hv.z, wh[0][6], g0b); g0b = fmaf(hv.w, wh[0][7], g0b);
        g1b = fmaf(hv.x, wh[1][4], g1b); g1b = fmaf(hv.y, wh[1][5], g1b);
        g1b = fmaf(hv.z, wh[1][6], g1b); g1b = fmaf(hv.w, wh[1][7], g1b);
      }
      float gs0 = bsum(g0a + g0b);
      float gs1 = bsum(g1a + g1b);
      if(lane == ib){ gvA=gs0; gvB=gs1; }
    }
    __syncthreads();   // staging region dead after this
  }
  // combine across the pair through LDS: comb[pair][half][16][2]
  float* comb = SM + 15360 + pairid*128;
  if(lane < 16){
    comb[half*32 + lane*2 + 0] = gvA + pg[0];
    comb[half*32 + lane*2 + 1] = gvB + pg[1];
  }
  __syncthreads();
  if(half == 0 && lane < 16){
    const int b = bh*16 + lane;
    float gi = comb[lane*2 + 0];
    float gf = comb[lane*2 + 1];
    float gG = comb[32 + lane*2 + 0];
    float go = comb[32 + lane*2 + 1];
    float c2 = sigm(gf)*cv + sigm(gi)*tanhf(gG);
    float h2 = sigm(go)*tanhf(c2);
    cv = c2;
    stc(&a.dhb[(size_t)((t+1)*3 + l)*BH_ + (size_t)b*H_ + jp], h2);
  }
}

template<int BF>
__device__ void dec2_body(const DecArgs2& a){
  __shared__ float SM[16384];
  const int tid  = threadIdx.x;
  const int lane = tid & 63;
  const int wid  = tid >> 6;                 // 0..7
  const int w4   = (blockIdx.x<<2) + (wid & 3);
  const int jp   = w4 & 511;
  const int bh   = w4 >> 9;
  const int half = wid >> 2;
  const int pairid = wid & 3;
  const int bh_blk = blockIdx.x >> 7;
  int g = a.gbase;

  float cvs[3];
  #pragma unroll
  for(int l=0;l<3;l++)
    cvs[l] = a.dcT[((size_t)l*H_ + jp)*32 + (size_t)bh*16 + (lane&15)];

  float wx[2][16], wh[2][8], pg[2];

  for(int t=0; t<64; ++t){
    // ---- Phase Z: z(t) from htop(t), fc(t-1) from same htop ----
    {
      const float* hs = (t==0) ? (a.dh0 + (size_t)2*BH_ + (size_t)bh_blk*16*H_)
                               : (a.dhb + (size_t)(t*3 + 2)*BH_ + (size_t)bh_blk*16*H_);
      for(int i=tid<<2; i<16*H_; i+=2048) *(float4*)&SM[i] = *(const float4*)&hs[i];
      __syncthreads();
      if(t < 63){
        float wz[8];
        size_t rz = (size_t)jp*1536;
        #pragma unroll
        for(int p=0;p<2;p++){
          float4 v = LD4<BF>(a.aW, rz + (lane<<2) + p*256);
          wz[p*4+0]=v.x; wz[p*4+1]=v.y; wz[p*4+2]=v.z; wz[p*4+3]=v.w;
        }
        for(int ib=half*8; ib<half*8+8; ib++){
          const float* hp = &SM[(ib<<9) + (lane<<2)];
          float aa = 0.f, ab = 0.f;
          {
            float4 hv = *(const float4*)(hp);
            aa = fmaf(hv.x, wz[0], aa); aa = fmaf(hv.y, wz[1], aa);
            aa = fmaf(hv.z, wz[2], aa); aa = fmaf(hv.w, wz[3], aa);
          }
          {
            float4 hv = *(const float4*)(hp + 256);
            ab = fmaf(hv.x, wz[4], ab); ab = fmaf(hv.y, wz[5], ab);
            ab = fmaf(hv.z, wz[6], ab); ab = fmaf(hv.w, wz[7], ab);
          }
          float acc = bsum(aa + ab);
          if(lane==0) stc(&a.zb[(size_t)t*BH_ + (size_t)(bh*16+ib)*H_ + jp], acc);
        }
      }
      if(t > 0){
        #pragma unroll
        for(int r=0;r<3;r++){
          const int q  = jp + (r<<9);
          const int v_ = q % 96;
          const int ib = q / 96;
          if((ib>>3) != half) continue;       // each output by exactly one wave
          float wf[8];
          size_t rf = (size_t)v_*H_;
          #pragma unroll
          for(int p=0;p<2;p++){
            float4 v = LD4<BF>(a.fW, rf + (lane<<2) + p*256);
            wf[p*4+0]=v.x; wf[p*4+1]=v.y; wf[p*4+2]=v.z; wf[p*4+3]=v.w;
          }
          const float* hp = &SM[(ib<<9) + (lane<<2)];
          float aa = 0.f, ab = 0.f;
          {
            float4 hv = *(const float4*)(hp);
            aa = fmaf(hv.x, wf[0], aa); aa = fmaf(hv.y, wf[1], aa);
            aa = fmaf(hv.z, wf[2], aa); aa = fmaf(hv.w, wf[3], aa);
          }
          {
            float4 hv = *(const float4*)(hp + 256);
            ab = fmaf(hv.x, wf[4], ab); ab = fmaf(hv.y, wf[5], ab);
            ab = fmaf(hv.z, wf[6], ab); ab = fmaf(hv.w, wf[7], ab);
          }
          float acc = bsum(aa + ab);
          if(lane==0){
            float rr = acc + LD<BF>(a.fb, v_);
            size_t oi = (size_t)(bh*16+ib)*(S_*V_) + (size_t)t*V_ + v_;
            if constexpr(BF) ((u16*)a.out)[oi] = f2b(rr);
            else             ((float*)a.out)[oi] = rr;
          }
        }
      }
    }
    if(t == 63) break;
    gbar(a.flags, ++g);

    // ---- Phase ATT (balanced): block n -> batch n>>3, ctx slice n&7.
    //      scores+softmax computed redundantly by the 8 blocks of a batch. ----
    {
      const int b  = blockIdx.x >> 3;
      const int ss = blockIdx.x & 7;
      float* Zs = SM; float* Ss = SM + 512;
      Zs[tid] = a.zb[(size_t)t*BH_ + (size_t)b*H_ + tid];
      __syncthreads();
      float wa[8];
      #pragma unroll
      for(int p=0;p<2;p++){
        float4 v = LD4<BF>(a.av, (lane<<2) + p*256);
        wa[p*4+0]=v.x; wa[p*4+1]=v.y; wa[p*4+2]=v.z; wa[p*4+3]=v.w;
      }
      for(int s=wid; s<64; s+=8){
        const float* ep = a.Epre + ((size_t)(s*B_ + b))*H_;
        float acc = 0.f;
        #pragma unroll
        for(int p=0;p<2;p++){
          const float4 e4 = *(const float4*)(ep + (lane<<2) + p*256);
          const float4 z4 = *(const float4*)(Zs + (lane<<2) + p*256);
          acc = fmaf(wa[p*4+0], tanhf(e4.x+z4.x), acc);
          acc = fmaf(wa[p*4+1], tanhf(e4.y+z4.y), acc);
          acc = fmaf(wa[p*4+2], tanhf(e4.z+z4.z), acc);
          acc = fmaf(wa[p*4+3], tanhf(e4.w+z4.w), acc);
        }
        acc = bsum(acc);
        if(lane==0) Ss[s] = acc;
      }
      __syncthreads();
      if(tid < 64){
        float vv = Ss[tid];
        float m = vv;
        #pragma unroll
        for(int off=1; off<64; off<<=1) m = fmaxf(m, __shfl_xor(m, off));
        float e = __expf(vv - m);
        float su = e;
        #pragma unroll
        for(int off=1; off<64; off<<=1) su += __shfl_xor(su, off);
        Ss[tid] = e / su;
      }
      __syncthreads();
      if(tid < 32){                        // 128-dim ctx slice: 32 float4 groups
        const int d4 = ss*128 + (tid<<2);
        float a0=0.f,a1=0.f,a2=0.f,a3=0.f;
        float b0=0.f,b1=0.f,b2=0.f,b3=0.f;
        const float* xb = a.X3 + (size_t)b*DIN_ + d4;
        for(int s=0;s<64;s+=2){
          const float pp = Ss[s];
          const float qq = Ss[s+1];
          const float4 xv = *(const float4*)(xb + (size_t)s*BDIN_);
          const float4 yv = *(const float4*)(xb + (size_t)(s+1)*BDIN_);
          a0 = fmaf(pp, xv.x, a0); a1 = fmaf(pp, xv.y, a1);
          a2 = fmaf(pp, xv.z, a2); a3 = fmaf(pp, xv.w, a3);
          b0 = fmaf(qq, yv.x, b0); b1 = fmaf(qq, yv.y, b1);
          b2 = fmaf(qq, yv.z, b2); b3 = fmaf(qq, yv.w, b3);
        }
        a0 += b0; a1 += b1; a2 += b2; a3 += b3;
        u16* cp = a.ctxb + (size_t)t*BDIN_ + (size_t)b*DIN_ + d4;
        unsigned lo = (unsigned)f2b(a0) | ((unsigned)f2b(a1)<<16);
        unsigned hi = (unsigned)f2b(a2) | ((unsigned)f2b(a3)<<16);
        stci((int*)cp, (int)lo);
        stci(((int*)cp)+1, (int)hi);
      }
    }
    gbar(a.flags, ++g);

    // ---- Phase PROJ ----
    {
      const u16* cs = a.ctxb + (size_t)t*BDIN_ + (size_t)bh_blk*16*DIN_;
      for(int i=tid*4; i<16*DIN_; i+=2048){          // conflict-free unpack
        ushort4 v = *(const ushort4*)(cs + i);
        *(float4*)&SM[i] = make_float4(bfu(v.x), bfu(v.y), bfu(v.z), bfu(v.w));
      }
      __syncthreads();
      float wpe[2][4], wpc[2][16];
      #pragma unroll
      for(int jj=0;jj<2;jj++){
        size_t row = (size_t)(jp + (jj<<9))*1280;
        float4 v = LD4<BF>(a.pW, row + (lane<<2));
        wpe[jj][0]=v.x; wpe[jj][1]=v.y; wpe[jj][2]=v.z; wpe[jj][3]=v.w;
        #pragma unroll
        for(int p=0;p<4;p++){
          float4 c4 = LD4<BF>(a.pW, row + 256 + (lane<<2) + p*256);
          wpc[jj][p*4+0]=c4.x; wpc[jj][p*4+1]=c4.y; wpc[jj][p*4+2]=c4.z; wpc[jj][p*4+3]=c4.w;
        }
      }
      const float pb0 = LD<BF>(a.pb, jp);
      const float pb1 = LD<BF>(a.pb, jp+512);
      for(int ib=half*8; ib<half*8+8; ib++){
        const int b = bh*16 + ib;
        const int tok = a.trg[b*S_ + t];
        float4 ev = LD4<BF>(a.emb, (size_t)tok*E_ + (lane<<2));
        float s0a=0.f, s0b=0.f, s1a=0.f, s1b=0.f;
        s0a = fmaf(ev.x, wpe[0][0], s0a); s0a = fmaf(ev.y, wpe[0][1], s0a);
        s0a = fmaf(ev.z, wpe[0][2], s0a); s0a = fmaf(ev.w, wpe[0][3], s0a);
        s1a = fmaf(ev.x, wpe[1][0], s1a); s1a = fmaf(ev.y, wpe[1][1], s1a);
        s1a = fmaf(ev.z, wpe[1][2], s1a); s1a = fmaf(ev.w, wpe[1][3], s1a);
        const float* cp = &SM[(ib<<10) + (lane<<2)];
        #pragma unroll
        for(int p=0;p<4;p++){
          float4 c4 = *(const float4*)(cp + p*256);
          if(p & 1){
            s0b = fmaf(c4.x, wpc[0][p*4+0], s0b); s0b = fmaf(c4.y, wpc[0][p*4+1], s0b);
            s0b = fmaf(c4.z, wpc[0][p*4+2], s0b); s0b = fmaf(c4.w, wpc[0][p*4+3], s0b);
            s1b = fmaf(c4.x, wpc[1][p*4+0], s1b); s1b = fmaf(c4.y, wpc[1][p*4+1], s1b);
            s1b = fmaf(c4.z, wpc[1][p*4+2], s1b); s1b = fmaf(c4.w, wpc[1][p*4+3], s1b);
          } else {
            s0a = fmaf(c4.x, wpc[0][p*4+0], s0a); s0a = fmaf(c4.y, wpc[0][p*4+1], s0a);
            s0a = fmaf(c4.z, wpc[0][p*4+2], s0a); s0a = fmaf(c4.w, wpc[0][p*4+3], s0a);
            s1a = fmaf(c4.x, wpc[1][p*4+0], s1a); s1a = fmaf(c4.y, wpc[1][p*4+1], s1a);
            s1a = fmaf(c4.z, wpc[1][p*4+2], s1a); s1a = fmaf(c4.w, wpc[1][p*4+3], s1a);
          }
        }
        float s0 = bsum(s0a + s0b);
        float s1 = bsum(s1a + s1b);
        if(lane==0){
          stc(&a.xpb[(size_t)t*BDIN_ + (size_t)b*DIN_ + jp],       s0 + pb0);
          stc(&a.xpb[(size_t)t*BDIN_ + (size_t)b*DIN_ + jp + 512], s1 + pb1);
        }
      }
      __syncthreads();
    }
    // ---- cells: gate-split, weights prefetched before each barrier ----
    dec_loadW<BF,4>(a, 0, jp, lane, half, wx, wh, pg);
    gbar(a.flags, ++g);
    dec_cellG<BF,4>(a, SM, t, 0, jp, bh, bh_blk, lane, tid, half, pairid, wx, wh, pg, cvs[0]);
    dec_loadW<BF,2>(a, 1, jp, lane, half, wx, wh, pg);
    gbar(a.flags, ++g);
    dec_cellG<BF,2>(a, SM, t, 1, jp, bh, bh_blk, lane, tid, half, pairid, wx, wh, pg, cvs[1]);
    dec_loadW<BF,2>(a, 2, jp, lane, half, wx, wh, pg);
    gbar(a.flags, ++g);
    dec_cellG<BF,2>(a, SM, t, 2, jp, bh, bh_blk, lane, tid, half, pairid, wx, wh, pg, cvs[2]);
    gbar(a.flags, ++g);
  }
}
__global__ __launch_bounds__(512,1) void k_dec2(DecArgs2 a){
  if(*a.fl) dec2_body<1>(a); else dec2_body<0>(a);
}

// ===========================================================================
// PLAN B fallback (small workspace): round-4 proven kernels, verbatim.
// ===========================================================================
struct EncArgsO {
  const float* G;
  const float* Xin;
  const void* Wih; size_t oWi;
  const void* Whh; size_t oWh;
  const void* bih; size_t obi;
  const void* bhh; size_t obh;
  float* hst; float* cT; float* Xout; float* dh; float* dcT;
  int l; const int* fl; int* flags; int gbase;
};

template<int BF, int CP>
__device__ void encO_body(const EncArgsO& a){
  __shared__ float SM[16384];
  const int tid  = threadIdx.x;
  const int w    = (blockIdx.x<<2) + (tid>>6);
  const int lane = tid & 63;
  const int d    = w >> 9;
  const int j    = w & 511;
  int g = a.gbase;

  float wh[4][8];
  #pragma unroll
  for(int gg=0; gg<4; gg++){
    size_t rowh = a.oWh + ((size_t)d*G4_ + (size_t)gg*H_ + j)*H_;
    #pragma unroll
    for(int p=0;p<2;p++){
      float4 v = LD4<BF>(a.Whh, rowh + (lane<<2) + p*256);
      wh[gg][p*4+0]=v.x; wh[gg][p*4+1]=v.y; wh[gg][p*4+2]=v.z; wh[gg][p*4+3]=v.w;
    }
  }
  float wxf[4][CP?CP*4:1];
  float pbias[4];
  if constexpr(CP>0){
    #pragma unroll
    for(int gg=0; gg<4; gg++){
      size_t rowx = a.oWi + ((size_t)d*G4_ + (size_t)gg*H_ + j)*DIN_;
      #pragma unroll
      for(int p=0;p<CP;p++){
        float4 v = LD4<BF>(a.Wih, rowx + (lane<<2) + p*256);
        wxf[gg][p*4+0]=v.x; wxf[gg][p*4+1]=v.y; wxf[gg][p*4+2]=v.z; wxf[gg][p*4+3]=v.w;
      }
    }
    size_t bb = (size_t)d*G4_ + j;
    #pragma unroll
    for(int gg=0;gg<4;gg++)
      pbias[gg] = LD<BF>(a.bih, a.obi + bb + (size_t)gg*H_)
                + LD<BF>(a.bhh, a.obh + bb + (size_t)gg*H_);
  }
  const int bE = lane & 31;
  const size_t ci = ((size_t)d*H_ + j)*32 + bE;
  float cv = 0.f;
  int cur = 0;
  for(int p=0;p<64;p++){
    const int t = d ? (63-p) : p;
    if(p == 0){
      for(int i=tid<<2; i<BH_; i+=1024) *(float4*)&SM[i] = make_float4(0.f,0.f,0.f,0.f);
    } else {
      const float* hsrc = a.hst + (size_t)((cur<<1)+d)*BH_;
      #pragma unroll 4
      for(int i=tid; i<BH_; i+=256) SM[i] = ldc(hsrc + i);
    }
    __syncthreads();
    float pg[4];
    if constexpr(CP==0){
      const float* Gp = a.G + (size_t)(t*B_+bE)*4096 + (size_t)d*G4_ + j;
      pg[0]=Gp[0]; pg[1]=Gp[512]; pg[2]=Gp[1024]; pg[3]=Gp[1536];
    } else {
      pg[0]=pbias[0]; pg[1]=pbias[1]; pg[2]=pbias[2]; pg[3]=pbias[3];
    }
    const float* xrow = nullptr;
    if constexpr(CP>0) xrow = a.Xin + (size_t)t*B_*DIN_;
    float gv0=0.f, gv1=0.f, gv2=0.f, gv3=0.f;
    for(int b=0;b<32;b++){
      float gs[4] = {0.f,0.f,0.f,0.f};
      const float* hp = &SM[(b<<9) + (lane<<2)];
      #pragma unroll
      for(int pp=0;pp<2;pp++){
        float4 hv = *(const float4*)(hp + pp*256);
        float ha[4] = {hv.x,hv.y,hv.z,hv.w};
        #pragma unroll
        for(int gg=0;gg<4;gg++){
          #pragma unroll
          for(int i=0;i<4;i++) gs[gg] = fmaf(ha[i], wh[gg][pp*4+i], gs[gg]);
        }
      }
      if constexpr(CP>0){
        const float* xr = xrow + (size_t)b*DIN_ + (lane<<2);
        #pragma unroll
        for(int pp=0;pp<CP;pp++){
          float4 xv = *(const float4*)(xr + pp*256);
          float xa[4] = {xv.x,xv.y,xv.z,xv.w};
          #pragma unroll
          for(int gg=0;gg<4;gg++){
            #pragma unroll
            for(int i=0;i<4;i++) gs[gg] = fmaf(xa[i], wxf[gg][pp*4+i], gs[gg]);
          }
        }
      }
      #pragma unroll
      for(int gg=0;gg<4;gg++) gs[gg] = bsum(gs[gg]);
      if(lane == b){ gv0=gs[0]; gv1=gs[1]; gv2=gs[2]; gv3=gs[3]; }
    }
    if(lane < 32){
      float gi = gv0+pg[0], gf = gv1+pg[1], gG = gv2+pg[2], go = gv3+pg[3];
      float c2 = sigm(gf)*cv + sigm(gi)*tanhf(gG);
      float h2 = sigm(go)*tanhf(c2);
      cv = c2;
      stc(&a.hst[(size_t)(((cur^1)<<1)+d)*BH_ + (size_t)bE*H_ + j], h2);
      a.Xout[(size_t)(t*B_+bE)*DIN_ + (d<<9) + j] = h2;
    }
    gbar(a.flags, ++g);
    cur ^= 1;
  }
  if(lane < 32) stc(&a.cT[ci], cv);
  gbar(a.flags, ++g);
  for(int i = blockIdx.x*256 + tid; i < BH_; i += 65536){
    a.dh[(size_t)a.l*BH_ + i]  = ldc(&a.hst[(size_t)(cur<<1)*BH_ + i])
                               + ldc(&a.hst[(size_t)((cur<<1)+1)*BH_ + i]);
    a.dcT[(size_t)a.l*BH_ + i] = ldc(&a.cT[i]) + ldc(&a.cT[BH_ + i]);
  }
}
__global__ __launch_bounds__(256,2) void k_enc_persF0(EncArgsO a){
  if(*a.fl) encO_body<1,1>(a); else encO_body<0,1>(a);
}
__global__ __launch_bounds__(256,2) void k_enc_persF12(EncArgsO a){
  if(*a.fl) encO_body<1,4>(a); else encO_body<0,4>(a);
}

struct DecArgsO {
  const int* trg;
  const void* emb; const void* aW; const void* av; const void* pW; const void* pb;
  const void* dWih; const void* dWhh; const void* dbih; const void* dbhh;
  const void* fW; const void* fb;
  const float* Epre; const float* X3;
  float* dh; float* dcT; float* z; float* ctx; float* xp;
  void* out; const int* fl; int* flags; int gbase;
};

template<int BF, int CP>
__device__ __forceinline__ void decO_cell(const DecArgsO& a, float* SM,
    const int l, const int cur, const int jp, const int bh, const int bh_blk,
    const int lane, const int tid, int& g, float& cv){
  constexpr int Kx = CP*256;
  constexpr int HB = (CP==4) ? 2 : 1;
  constexpr int NB = 16/HB;
  const float* xsrc = (l==0) ? (a.xp + (size_t)bh_blk*16*DIN_)
                             : (a.dh + ((size_t)(cur^1)*3 + (l-1))*BH_ + (size_t)bh_blk*16*H_);
  const float* hsrc = a.dh + ((size_t)cur*3 + l)*BH_ + (size_t)bh_blk*16*H_;
  float wx[4][CP*4];
  float wh[4][8];
  #pragma unroll
  for(int gg=0; gg<4; gg++){
    size_t rowx = ((size_t)l*G4_ + (size_t)gg*H_ + jp)*DIN_;
    #pragma unroll
    for(int p=0;p<CP;p++){
      float4 v = LD4<BF>(a.dWih, rowx + (lane<<2) + p*256);
      wx[gg][p*4+0]=v.x; wx[gg][p*4+1]=v.y; wx[gg][p*4+2]=v.z; wx[gg][p*4+3]=v.w;
    }
    size_t rowh = ((size_t)l*G4_ + (size_t)gg*H_ + jp)*H_;
    #pragma unroll
    for(int p=0;p<2;p++){
      float4 v = LD4<BF>(a.dWhh, rowh + (lane<<2) + p*256);
      wh[gg][p*4+0]=v.x; wh[gg][p*4+1]=v.y; wh[gg][p*4+2]=v.z; wh[gg][p*4+3]=v.w;
    }
  }
  float pg[4];
  {
    size_t bb = (size_t)l*G4_ + jp;
    #pragma unroll
    for(int gg=0;gg<4;gg++)
      pg[gg] = LD<BF>(a.dbih, bb + (size_t)gg*H_) + LD<BF>(a.dbhh, bb + (size_t)gg*H_);
  }
  float gv0=0.f,gv1=0.f,gv2=0.f,gv3=0.f;
  #pragma unroll
  for(int hf=0; hf<HB; hf++){
    const float* xg = xsrc + (size_t)hf*NB*Kx;
    const float* hg = hsrc + (size_t)hf*NB*H_;
    #pragma unroll 4
    for(int i=tid; i<NB*Kx; i+=256) SM[i] = ldc(xg + i);
    #pragma unroll 4
    for(int i=tid; i<NB*H_; i+=256) SM[NB*Kx + i] = ldc(hg + i);
    __syncthreads();
    for(int ib2=0; ib2<NB; ib2++){
      const int ib = hf*NB + ib2;
      float gs[4] = {0.f,0.f,0.f,0.f};
      const float* xr = &SM[ib2*Kx + (lane<<2)];
      #pragma unroll
      for(int p=0;p<CP;p++){
        float4 xv = *(const float4*)(xr + p*256);
        float xa[4] = {xv.x,xv.y,xv.z,xv.w};
        #pragma unroll
        for(int gg=0;gg<4;gg++){
          #pragma unroll
          for(int i=0;i<4;i++) gs[gg] = fmaf(xa[i], wx[gg][p*4+i], gs[gg]);
        }
      }
      const float* hr = &SM[NB*Kx + ib2*H_ + (lane<<2)];
      #pragma unroll
      for(int p=0;p<2;p++){
        float4 hv = *(const float4*)(hr + p*256);
        float ha[4] = {hv.x,hv.y,hv.z,hv.w};
        #pragma unroll
        for(int gg=0;gg<4;gg++){
          #pragma unroll
          for(int i=0;i<4;i++) gs[gg] = fmaf(ha[i], wh[gg][p*4+i], gs[gg]);
        }
      }
      #pragma unroll
      for(int gg=0;gg<4;gg++) gs[gg] = bsum(gs[gg]);
      if(lane == ib){ gv0=gs[0]; gv1=gs[1]; gv2=gs[2]; gv3=gs[3]; }
    }
    __syncthreads();
  }
  if(lane < 16){
    const int b = bh*16 + lane;
    float gi = gv0+pg[0], gf = gv1+pg[1], gG = gv2+pg[2], go = gv3+pg[3];
    float c2 = sigm(gf)*cv + sigm(gi)*tanhf(gG);
    float h2 = sigm(go)*tanhf(c2);
    cv = c2;
    stc(&a.dh[((size_t)(cur^1)*3 + l)*BH_ + (size_t)b*H_ + jp], h2);
  }
  gbar(a.flags, ++g);
}

template<int BF>
__device__ void decO_body(const DecArgsO& a){
  __shared__ float SM[16384];
  const int tid  = threadIdx.x;
  const int w    = (blockIdx.x<<2) + (tid>>6);
  const int lane = tid & 63;
  const int jp   = w & 511;
  const int bh   = w >> 9;
  const int bh_blk = blockIdx.x >> 7;
  int g = a.gbase;
  float cvs[3];
  #pragma unroll
  for(int l=0;l<3;l++)
    cvs[l] = a.dcT[((size_t)l*H_ + jp)*32 + (size_t)bh*16 + (lane&15)];
  int cur = 0;
  for(int t=0; t<64; ++t){
    {
      const float* hs = a.dh + ((size_t)cur*3 + 2)*BH_ + (size_t)bh_blk*16*H_;
      #pragma unroll 4
      for(int i=tid; i<16*H_; i+=256) SM[i] = ldc(hs + i);
      __syncthreads();
      if(t < 63){
        float wz[8];
        size_t rz = (size_t)jp*1536;
        #pragma unroll
        for(int p=0;p<2;p++){
          float4 v = LD4<BF>(a.aW, rz + (lane<<2) + p*256);
          wz[p*4+0]=v.x; wz[p*4+1]=v.y; wz[p*4+2]=v.z; wz[p*4+3]=v.w;
        }
        for(int ib=0; ib<16; ib++){
          const float* hp = &SM[(ib<<9) + (lane<<2)];
          float acc = 0.f;
          #pragma unroll
          for(int p=0;p<2;p++){
            float4 hv = *(const float4*)(hp + p*256);
            acc = fmaf(hv.x, wz[p*4+0], acc); acc = fmaf(hv.y, wz[p*4+1], acc);
            acc = fmaf(hv.z, wz[p*4+2], acc); acc = fmaf(hv.w, wz[p*4+3], acc);
          }
          acc = bsum(acc);
          if(lane==0) stc(&a.z[(size_t)(bh*16+ib)*H_ + jp], acc);
        }
      }
      if(t > 0){
        #pragma unroll
        for(int r=0;r<3;r++){
          const int q  = jp + (r<<9);
          const int v_ = q % 96;
          const int ib = q / 96;
          float wf[8];
          size_t rf = (size_t)v_*H_;
          #pragma unroll
          for(int p=0;p<2;p++){
            float4 v = LD4<BF>(a.fW, rf + (lane<<2) + p*256);
            wf[p*4+0]=v.x; wf[p*4+1]=v.y; wf[p*4+2]=v.z; wf[p*4+3]=v.w;
          }
          const float* hp = &SM[(ib<<9) + (lane<<2)];
          float acc = 0.f;
          #pragma unroll
          for(int p=0;p<2;p++){
            float4 hv = *(const float4*)(hp + p*256);
            acc = fmaf(hv.x, wf[p*4+0], acc); acc = fmaf(hv.y, wf[p*4+1], acc);
            acc = fmaf(hv.z, wf[p*4+2], acc); acc = fmaf(hv.w, wf[p*4+3], acc);
          }
          acc = bsum(acc);
          if(lane==0){
            float rr = acc + LD<BF>(a.fb, v_);
            size_t oi = (size_t)(bh*16+ib)*(S_*V_) + (size_t)t*V_ + v_;
            if constexpr(BF) ((u16*)a.out)[oi] = f2b(rr);
            else             ((float*)a.out)[oi] = rr;
          }
        }
      }
    }
    if(t == 63) break;
    gbar(a.flags, ++g);
    if(blockIdx.x < 32){
      const int b = blockIdx.x;
      float* Zs = SM; float* Ss = SM + 512;
      for(int i=tid; i<512; i+=256) Zs[i] = ldc(a.z + (size_t)b*H_ + i);
      __syncthreads();
      float wa[8];
      #pragma unroll
      for(int p=0;p<2;p++){
        float4 v = LD4<BF>(a.av, (lane<<2) + p*256);
        wa[p*4+0]=v.x; wa[p*4+1]=v.y; wa[p*4+2]=v.z; wa[p*4+3]=v.w;
      }
      const int ww = tid>>6;
      for(int s=ww; s<64; s+=4){
        const float* ep = a.Epre + ((size_t)(s*B_ + b))*H_;
        float acc = 0.f;
        #pragma unroll
        for(int p=0;p<2;p++){
          const float4 e4 = *(const float4*)(ep + (lane<<2) + p*256);
          const float4 z4 = *(const float4*)(Zs + (lane<<2) + p*256);
          acc = fmaf(wa[p*4+0], tanhf(e4.x+z4.x), acc);
          acc = fmaf(wa[p*4+1], tanhf(e4.y+z4.y), acc);
          acc = fmaf(wa[p*4+2], tanhf(e4.z+z4.z), acc);
          acc = fmaf(wa[p*4+3], tanhf(e4.w+z4.w), acc);
        }
        acc = bsum(acc);
        if(lane==0) Ss[s] = acc;
      }
      __syncthreads();
      if(tid < 64){
        float vv = Ss[tid];
        float m = vv;
        #pragma unroll
        for(int off=1; off<64; off<<=1) m = fmaxf(m, __shfl_xor(m, off));
        float e = __expf(vv - m);
        float su = e;
        #pragma unroll
        for(int off=1; off<64; off<<=1) su += __shfl_xor(su, off);
        Ss[tid] = e / su;
      }
      __syncthreads();
      for(int d4 = tid<<2; d4 < DIN_; d4 += 1024){
        float a0=0.f,a1=0.f,a2=0.f,a3=0.f;
        const float* xb = a.X3 + (size_t)b*DIN_ + d4;
        for(int s=0;s<64;s++){
          const float pp = Ss[s];
          const float4 xv = *(const float4*)(xb + (size_t)s*BDIN_);
          a0 = fmaf(pp, xv.x, a0); a1 = fmaf(pp, xv.y, a1);
          a2 = fmaf(pp, xv.z, a2); a3 = fmaf(pp, xv.w, a3);
        }
        float* cp = &a.ctx[(size_t)b*DIN_ + d4];
        stc(cp+0, a0); stc(cp+1, a1); stc(cp+2, a2); stc(cp+3, a3);
      }
    }
    gbar(a.flags, ++g);
    {
      const float* cs = a.ctx + (size_t)bh_blk*16*DIN_;
      #pragma unroll 4
      for(int i=tid; i<16*DIN_; i+=256) SM[i] = ldc(cs + i);
      __syncthreads();
      float wpe[2][4], wpc[2][16];
      #pragma unroll
      for(int jj=0;jj<2;jj++){
        size_t row = (size_t)(jp + (jj<<9))*1280;
        float4 v = LD4<BF>(a.pW, row + (lane<<2));
        wpe[jj][0]=v.x; wpe[jj][1]=v.y; wpe[jj][2]=v.z; wpe[jj][3]=v.w;
        #pragma unroll
        for(int p=0;p<4;p++){
          float4 c4 = LD4<BF>(a.pW, row + 256 + (lane<<2) + p*256);
          wpc[jj][p*4+0]=c4.x; wpc[jj][p*4+1]=c4.y; wpc[jj][p*4+2]=c4.z; wpc[jj][p*4+3]=c4.w;
        }
      }
      const float pb0 = LD<BF>(a.pb, jp);
      const float pb1 = LD<BF>(a.pb, jp+512);
      for(int ib=0; ib<16; ib++){
        const int b = bh*16 + ib;
        const int tok = a.trg[b*S_ + t];
        float4 ev = LD4<BF>(a.emb, (size_t)tok*E_ + (lane<<2));
        float ea[4] = {ev.x, ev.y, ev.z, ev.w};
        float s0=0.f, s1=0.f;
        #pragma unroll
        for(int i=0;i<4;i++){ s0 = fmaf(ea[i], wpe[0][i], s0); s1 = fmaf(ea[i], wpe[1][i], s1); }
        const float* cp = &SM[(ib<<10) + (lane<<2)];
        #pragma unroll
        for(int p=0;p<4;p++){
          float4 c4 = *(const float4*)(cp + p*256);
          float ca[4] = {c4.x,c4.y,c4.z,c4.w};
          #pragma unroll
          for(int i=0;i<4;i++){ s0 = fmaf(ca[i], wpc[0][p*4+i], s0); s1 = fmaf(ca[i], wpc[1][p*4+i], s1); }
        }
        s0 = bsum(s0); s1 = bsum(s1);
        if(lane==0){
          stc(&a.xp[(size_t)b*DIN_ + jp],       s0 + pb0);
          stc(&a.xp[(size_t)b*DIN_ + jp + 512], s1 + pb1);
        }
      }
    }
    gbar(a.flags, ++g);
    decO_cell<BF,4>(a, SM, 0, cur, jp, bh, bh_blk, lane, tid, g, cvs[0]);
    decO_cell<BF,2>(a, SM, 1, cur, jp, bh, bh_blk, lane, tid, g, cvs[1]);
    decO_cell<BF,2>(a, SM, 2, cur, jp, bh, bh_blk, lane, tid, g, cvs[2]);
    cur ^= 1;
  }
}
__global__ __launch_bounds__(256,2) void k_dec_persO(DecArgsO a){
  if(*a.fl) decO_body<1>(a); else decO_body<0>(a);
}

// ---------------------------------------------------------------------------
extern "C" void kernel_launch(void* const* d_in, const int* in_sizes, int n_in,
                              void* d_out, int out_size, void* d_ws, size_t ws_size,
                              hipStream_t stream){
  const int* src  = (const int*)d_in[0];
  const int* trg  = (const int*)d_in[1];
  const void* emb = d_in[2];
  const void* eWih= d_in[3];
  const void* eWhh= d_in[4];
  const void* ebih= d_in[5];
  const void* ebhh= d_in[6];
  const void* dWih= d_in[7];
  const void* dWhh= d_in[8];
  const void* dbih= d_in[9];
  const void* dbhh= d_in[10];
  const void* aW  = d_in[11];
  const void* ab  = d_in[12];
  const void* av  = d_in[13];
  const void* pW  = d_in[14];
  const void* pb  = d_in[15];
  const void* fW  = d_in[16];
  const void* fb  = d_in[17];

  char* base = (char*)d_ws;
  size_t off = 0;
  auto take = [&](size_t bytes)->char*{
    char* p = base + off; off = (off + bytes + 255) & ~(size_t)255; return p;
  };

  const size_t szX  = (size_t)2048*1024*4;   // 8 MB
  const size_t szG  = (size_t)2048*4096*4;   // 32 MB
  const size_t szE  = (size_t)2048*512*4;    // 4 MB
  int planA = ws_size >= (size_t)53*1024*1024;

  if(planA){
    float* X    = (float*)take(szX);               // Xin/Xout in-place
    float* Xh   = (float*)take(szX);               // henc: 64 slots * 2 * BH * 4 = 8 MB
    float* G    = (float*)take(szG);
    // decoder t-indexed buffers overlay G (dead after encoder):
    float* dhb  = G;                               // 64*3*BH f
    float* zb   = dhb + (size_t)64*3*BH_;          // 63*BH f
    float* xpb  = zb  + (size_t)63*BH_;            // 63*B*DIN f
    u16*   ctxb = (u16*)(xpb + (size_t)63*BDIN_);  // 63*B*DIN u16   total 29.1 MB <= 32
    float* Epre = (float*)take(szE);
    float* cTe  = (float*)take((size_t)2*BH_*4);
    float* dh0  = (float*)take((size_t)3*BH_*4);
    float* dcT  = (float*)take((size_t)3*BH_*4);
    int* fl     = (int*)take(256);
    int* flags  = (int*)take((256*FSTRIDE + 16)*4);

    k_detect<<<1, 256, 0, stream>>>(av, fl, flags);
    k_embed<<<8192, 256, 0, stream>>>(src, emb, X, fl);

    for(int l=0;l<L_;l++){
      int K = (l==0) ? E_ : DIN_;
      k_gemm<<<dim3(64,16), 256, 0, stream>>>(X, DIN_,
          eWih, DIN_, (size_t)l*2*G4_*DIN_,
          ebih, (size_t)l*2*G4_, ebhh, (size_t)l*2*G4_,
          G, 4096, K, fl);
      EncArgs2 ea;
      ea.G = G; ea.Whh = eWhh; ea.oWh = (size_t)l*2*G4_*H_;
      ea.henc = Xh; ea.cT = cTe; ea.Xout = X;
      ea.dh0 = dh0; ea.dcT = dcT; ea.l = l;
      ea.fl = fl; ea.flags = flags; ea.gbase = l*65;
      k_enc2<<<256, 512, 0, stream>>>(ea);
    }
    k_gemm<<<dim3(8,16), 256, 0, stream>>>(X, DIN_,
        aW, 3*H_, (size_t)H_, ab, 0, nullptr, 0, Epre, H_, DIN_, fl);
    k_outzero<<<12, 256, 0, stream>>>(d_out, fl);

    DecArgs2 da;
    da.trg = trg; da.emb = emb; da.aW = aW; da.av = av; da.pW = pW; da.pb = pb;
    da.dWih = dWih; da.dWhh = dWhh; da.dbih = dbih; da.dbhh = dbhh;
    da.fW = fW; da.fb = fb;
    da.Epre = Epre; da.X3 = X;
    da.dh0 = dh0; da.dhb = dhb; da.zb = zb; da.ctxb = ctxb; da.xpb = xpb;
    da.dcT = dcT; da.out = d_out; da.fl = fl; da.flags = flags; da.gbase = 3*65;
    k_dec2<<<256, 512, 0, stream>>>(da);
  } else {
    // -------- fallback: round-4 proven path (fused encoder + ldc decoder) --------
    float* XA   = (float*)take(szX);
    float* XB   = (float*)take(szX);
    float* Epre = (float*)take(szE);
    float* hst  = (float*)take((size_t)4*BH_*4);
    float* cTe  = (float*)take((size_t)2*BH_*4);
    float* dh   = (float*)take((size_t)6*BH_*4);
    float* dcT  = (float*)take((size_t)3*BH_*4);
    float* zbuf = (float*)take((size_t)BH_*4);
    float* ctx  = (float*)take((size_t)2*BH_*4);
    float* xp   = (float*)take((size_t)2*BH_*4);
    int* fl     = (int*)take(256);
    int* flags  = (int*)take((256*FSTRIDE + 16)*4);

    k_detect<<<1, 256, 0, stream>>>(av, fl, flags);
    k_embed<<<8192, 256, 0, stream>>>(src, emb, XA, fl);

    float* Xin = XA; float* Xout = XB;
    for(int l=0;l<L_;l++){
      EncArgsO ea;
      ea.G = nullptr; ea.Xin = Xin;
      ea.Wih = eWih; ea.oWi = (size_t)l*2*G4_*DIN_;
      ea.Whh = eWhh; ea.oWh = (size_t)l*2*G4_*H_;
      ea.bih = ebih; ea.obi = (size_t)l*2*G4_;
      ea.bhh = ebhh; ea.obh = (size_t)l*2*G4_;
      ea.hst = hst; ea.cT = cTe; ea.Xout = Xout;
      ea.dh = dh; ea.dcT = dcT; ea.l = l;
      ea.fl = fl; ea.flags = flags; ea.gbase = l*65;
      if(l == 0) k_enc_persF0<<<256, 256, 0, stream>>>(ea);
      else       k_enc_persF12<<<256, 256, 0, stream>>>(ea);
      float* tmp = Xin; Xin = Xout; Xout = tmp;
    }
    k_gemm<<<dim3(8,16), 256, 0, stream>>>(Xin, DIN_,
        aW, 3*H_, (size_t)H_, ab, 0, nullptr, 0, Epre, H_, DIN_, fl);
    k_outzero<<<12, 256, 0, stream>>>(d_out, fl);

    DecArgsO da;
    da.trg = trg; da.emb = emb; da.aW = aW; da.av = av; da.pW = pW; da.pb = pb;
    da.dWih = dWih; da.dWhh = dWhh; da.dbih = dbih; da.dbhh = dbhh;
    da.fW = fW; da.fb = fb;
    da.Epre = Epre; da.X3 = Xin;
    da.dh = dh; da.dcT = dcT; da.z = zbuf; da.ctx = ctx; da.xp = xp;
    da.out = d_out; da.fl = fl; da.flags = flags; da.gbase = 3*65;
    k_dec_persO<<<256, 256, 0, stream>>>(da);
  }
}